// Round 1
// baseline (521.544 us; speedup 1.0000x reference)
//
#include <hip/hip_runtime.h>

constexpr int NNODES = 50000;

// ---------------- CSR build ----------------

__global__ void __launch_bounds__(256) hist_kernel(const int* __restrict__ ei, int E,
                                                   int* __restrict__ cs, int* __restrict__ cd) {
  int e = blockIdx.x * 256 + threadIdx.x;
  if (e >= E) return;
  atomicAdd(&cs[ei[e]], 1);       // src degree (reference: deg over src)
  atomicAdd(&cd[ei[E + e]], 1);   // dst in-degree (CSR rows)
}

__global__ void __launch_bounds__(256) dis_kernel(const int* __restrict__ cs,
                                                  float* __restrict__ dis, int N) {
  int n = blockIdx.x * 256 + threadIdx.x;
  if (n >= N) return;
  int c = cs[n];
  dis[n] = (c > 0) ? rsqrtf((float)c) : 0.0f;
}

__global__ void __launch_bounds__(256) scan1_kernel(const int* __restrict__ cnt,
                                                    int* __restrict__ exc,
                                                    int* __restrict__ bsum, int N) {
  __shared__ int sh[256];
  int tid = threadIdx.x;
  int i = blockIdx.x * 256 + tid;
  int v = (i < N) ? cnt[i] : 0;
  int acc = v;
  sh[tid] = acc; __syncthreads();
  #pragma unroll
  for (int off = 1; off < 256; off <<= 1) {
    int t = (tid >= off) ? sh[tid - off] : 0;
    __syncthreads();
    acc += t;
    sh[tid] = acc;
    __syncthreads();
  }
  if (i < N) exc[i] = acc - v;               // exclusive within block
  if (tid == 255) bsum[blockIdx.x] = acc;    // block total
}

__global__ void __launch_bounds__(256) scan2_kernel(int* __restrict__ bsum, int NB) {
  __shared__ int sh[256];
  int tid = threadIdx.x;
  int v = (tid < NB) ? bsum[tid] : 0;
  int acc = v;
  sh[tid] = acc; __syncthreads();
  #pragma unroll
  for (int off = 1; off < 256; off <<= 1) {
    int t = (tid >= off) ? sh[tid - off] : 0;
    __syncthreads();
    acc += t;
    sh[tid] = acc;
    __syncthreads();
  }
  if (tid < NB) bsum[tid] = acc - v;         // exclusive block offsets (in place)
}

__global__ void __launch_bounds__(256) scan3_kernel(int* __restrict__ exc,
                                                    const int* __restrict__ bsum, int N) {
  int i = blockIdx.x * 256 + threadIdx.x;
  if (i < N) exc[i] += bsum[blockIdx.x];
}

__global__ void __launch_bounds__(256) fill_kernel(const int* __restrict__ ei, int E,
                                                   const int* __restrict__ start,
                                                   int* __restrict__ cursor,
                                                   const float* __restrict__ dis,
                                                   int* __restrict__ col,
                                                   float* __restrict__ wp) {
  int e = blockIdx.x * 256 + threadIdx.x;
  if (e >= E) return;
  int s = ei[e], d = ei[E + e];
  int pos = start[d] + atomicAdd(&cursor[d], 1);
  col[pos] = s;
  wp[pos] = -dis[s] * dis[d];   // pre-negated: lap = sum(wp * v[src])
}

// ---------------- Fused 3-way GEMM ----------------
// A = x@W[0] - x@W[2] + b ; U = x@W[1] ; V = x@W[2]

template<int FIN, int FOUT, int RPT>
__global__ void __launch_bounds__(256) gemm3_kernel(const float* __restrict__ x,
    const float* __restrict__ W, const float* __restrict__ b,
    float* __restrict__ A, float* __restrict__ U, float* __restrict__ V, int N) {
  constexpr int TG = 256 / FOUT;
  constexpr int ROWS = TG * RPT;
  __shared__ float xs[ROWS][FIN + 4];
  const int c = threadIdx.x % FOUT;
  const int rg = threadIdx.x / FOUT;
  const int row0 = blockIdx.x * ROWS;
  for (int i = threadIdx.x * 4; i < ROWS * FIN; i += 256 * 4) {
    int r = i / FIN, k = i - r * FIN;
    float4 v = make_float4(0.f, 0.f, 0.f, 0.f);
    if (row0 + r < N) v = *(const float4*)(x + (size_t)(row0 + r) * FIN + k);
    *(float4*)(&xs[r][k]) = v;
  }
  __syncthreads();
  float acc0[RPT], acc1[RPT], acc2[RPT];
  #pragma unroll
  for (int r = 0; r < RPT; ++r) { acc0[r] = 0.f; acc1[r] = 0.f; acc2[r] = 0.f; }
  const float* W0p = W + c;
  const float* W1p = W + FIN * FOUT + c;
  const float* W2p = W + 2 * FIN * FOUT + c;
  for (int k = 0; k < FIN; ++k) {
    float w0 = W0p[k * FOUT];
    float w1 = W1p[k * FOUT];
    float w2 = W2p[k * FOUT];
    #pragma unroll
    for (int r = 0; r < RPT; ++r) {
      float xv = xs[rg * RPT + r][k];
      acc0[r] = fmaf(xv, w0, acc0[r]);
      acc1[r] = fmaf(xv, w1, acc1[r]);
      acc2[r] = fmaf(xv, w2, acc2[r]);
    }
  }
  const float bb = b[c];
  #pragma unroll
  for (int r = 0; r < RPT; ++r) {
    int row = row0 + rg * RPT + r;
    if (row < N) {
      size_t o = (size_t)row * FOUT + c;
      A[o] = acc0[r] - acc2[r] + bb;
      U[o] = acc1[r];
      V[o] = acc2[r];
    }
  }
}

// ---------------- Laplacian propagation (CSR gather, no atomics) ----------------

template<int F>
__global__ void __launch_bounds__(256) lap1_kernel(const float* __restrict__ V,
    const int* __restrict__ start, const int* __restrict__ cnt,
    const int* __restrict__ col, const float* __restrict__ wp,
    float* __restrict__ Z, int N) {
  int t = blockIdx.x * 256 + threadIdx.x;
  int n = t / F;
  if (n >= N) return;
  int f = t & (F - 1);
  int j = start[n], e = j + cnt[n];
  float acc = 0.f;
  for (; j + 3 < e; j += 4) {
    int s0 = col[j], s1 = col[j + 1], s2 = col[j + 2], s3 = col[j + 3];
    float w0 = wp[j], w1 = wp[j + 1], w2 = wp[j + 2], w3 = wp[j + 3];
    float v0 = V[(size_t)s0 * F + f];
    float v1 = V[(size_t)s1 * F + f];
    float v2 = V[(size_t)s2 * F + f];
    float v3 = V[(size_t)s3 * F + f];
    acc = fmaf(w0, v0, acc); acc = fmaf(w1, v1, acc);
    acc = fmaf(w2, v2, acc); acc = fmaf(w3, v3, acc);
  }
  for (; j < e; ++j) {
    int s = col[j];
    acc = fmaf(wp[j], V[(size_t)s * F + f], acc);
  }
  Z[t] = acc;
}

// out = A + L(U + 2Z), optional relu; fully owned per-thread write.
template<int F, bool RELU>
__global__ void __launch_bounds__(256) lap2_kernel(const float* __restrict__ U,
    const float* __restrict__ Z, const float* __restrict__ A,
    const int* __restrict__ start, const int* __restrict__ cnt,
    const int* __restrict__ col, const float* __restrict__ wp,
    float* __restrict__ out, int N) {
  int t = blockIdx.x * 256 + threadIdx.x;
  int n = t / F;
  if (n >= N) return;
  int f = t & (F - 1);
  int j = start[n], e = j + cnt[n];
  float acc = 0.f;
  for (; j + 1 < e; j += 2) {
    int s0 = col[j], s1 = col[j + 1];
    float w0 = wp[j], w1 = wp[j + 1];
    size_t o0 = (size_t)s0 * F + f, o1 = (size_t)s1 * F + f;
    float v0 = fmaf(2.f, Z[o0], U[o0]);
    float v1 = fmaf(2.f, Z[o1], U[o1]);
    acc = fmaf(w0, v0, acc);
    acc = fmaf(w1, v1, acc);
  }
  if (j < e) {
    int s = col[j];
    size_t o = (size_t)s * F + f;
    acc = fmaf(wp[j], fmaf(2.f, Z[o], U[o]), acc);
  }
  float r = A[t] + acc;
  if (RELU) r = fmaxf(r, 0.f);
  out[t] = r;
}

// ---------------- launch ----------------

extern "C" void kernel_launch(void* const* d_in, const int* in_sizes, int n_in,
                              void* d_out, int out_size, void* d_ws, size_t ws_size,
                              hipStream_t stream) {
  const float* x  = (const float*)d_in[0];
  const int*   ei = (const int*)d_in[1];
  const float* W1 = (const float*)d_in[2];
  const float* b1 = (const float*)d_in[3];
  const float* Wm = (const float*)d_in[4];
  const float* bm = (const float*)d_in[5];
  const float* W2 = (const float*)d_in[6];
  const float* b2 = (const float*)d_in[7];
  float* out = (float*)d_out;
  const int N = NNODES;
  const int E = in_sizes[1] / 2;
  const int NB = (N + 255) / 256;  // 196

  char* p = (char*)d_ws;
  auto alloc = [&](size_t bytes) -> char* {
    char* q = p;
    p += (bytes + 255) & ~(size_t)255;
    return q;
  };
  int*   cnt_src = (int*)alloc((size_t)N * 4);
  int*   cnt_dst = (int*)alloc((size_t)N * 4);
  int*   cursor  = (int*)alloc((size_t)N * 4);
  int*   startv  = (int*)alloc((size_t)N * 4);
  int*   bsum    = (int*)alloc(1024);
  float* dis     = (float*)alloc((size_t)N * 4);
  int*   col     = (int*)alloc((size_t)E * 4);
  float* wp      = (float*)alloc((size_t)E * 4);
  float* A1      = (float*)alloc((size_t)N * 64 * 4);
  float* A2      = (float*)alloc((size_t)N * 64 * 4);
  float* Ub      = (float*)alloc((size_t)N * 64 * 4);
  float* Vb      = (float*)alloc((size_t)N * 64 * 4);
  float* Zb      = (float*)alloc((size_t)N * 64 * 4);

  hipMemsetAsync(cnt_src, 0, (size_t)N * 4, stream);
  hipMemsetAsync(cnt_dst, 0, (size_t)N * 4, stream);
  hipMemsetAsync(cursor,  0, (size_t)N * 4, stream);

  int eb = (E + 255) / 256;
  hist_kernel<<<eb, 256, 0, stream>>>(ei, E, cnt_src, cnt_dst);
  dis_kernel<<<NB, 256, 0, stream>>>(cnt_src, dis, N);
  scan1_kernel<<<NB, 256, 0, stream>>>(cnt_dst, startv, bsum, N);
  scan2_kernel<<<1, 256, 0, stream>>>(bsum, NB);
  scan3_kernel<<<NB, 256, 0, stream>>>(startv, bsum, N);
  fill_kernel<<<eb, 256, 0, stream>>>(ei, E, startv, cursor, dis, col, wp);

  int gb32 = (N + 31) / 32;        // 1563
  int g64  = (N * 64 + 255) / 256; // 12500
  int g16  = (N * 16 + 255) / 256; // 3125

  // Layer 1: 128 -> 64, relu
  gemm3_kernel<128, 64, 8><<<gb32, 256, 0, stream>>>(x, W1, b1, A1, Ub, Vb, N);
  lap1_kernel<64><<<g64, 256, 0, stream>>>(Vb, startv, cnt_dst, col, wp, Zb, N);
  lap2_kernel<64, true><<<g64, 256, 0, stream>>>(Ub, Zb, A1, startv, cnt_dst, col, wp, A1, N);

  // Layer 2: 64 -> 64, relu
  gemm3_kernel<64, 64, 8><<<gb32, 256, 0, stream>>>(A1, Wm, bm, A2, Ub, Vb, N);
  lap1_kernel<64><<<g64, 256, 0, stream>>>(Vb, startv, cnt_dst, col, wp, Zb, N);
  lap2_kernel<64, true><<<g64, 256, 0, stream>>>(Ub, Zb, A2, startv, cnt_dst, col, wp, A2, N);

  // Layer 3: 64 -> 16, no relu, straight to d_out
  gemm3_kernel<64, 16, 2><<<gb32, 256, 0, stream>>>(A2, W2, b2, A1, Ub, Vb, N);
  lap1_kernel<16><<<g16, 256, 0, stream>>>(Vb, startv, cnt_dst, col, wp, Zb, N);
  lap2_kernel<16, false><<<g16, 256, 0, stream>>>(Ub, Zb, A1, startv, cnt_dst, col, wp, out, N);
}

// Round 2
// 465.467 us; speedup vs baseline: 1.1205x; 1.1205x over previous
//
#include <hip/hip_runtime.h>

constexpr int NNODES = 50000;
constexpr int NS  = 32;     // edge slices
constexpr int NR  = 4;      // node ranges
constexpr int RSZ = 12500;  // nodes per range (NR*RSZ >= NNODES)

// ---------------- CSR build: LDS partial histograms, zero global atomics ----------------

// grid (NS, NR, 2). z=0: src counts (for dis), z=1: dst counts (CSR rows).
__global__ void __launch_bounds__(256) hist_kernel(const int* __restrict__ ei, int E, int ES,
                                                   int* __restrict__ part_src,
                                                   int* __restrict__ part_dst) {
  __shared__ int sh[RSZ];
  for (int i = threadIdx.x; i < RSZ; i += 256) sh[i] = 0;
  __syncthreads();
  const int s = blockIdx.x, r = blockIdx.y, z = blockIdx.z;
  const int lo = r * RSZ;
  const int* __restrict__ idxarr = ei + (z ? E : 0);
  const int e0 = s * ES, e1 = min(e0 + ES, E);
  for (int e = e0 + (int)threadIdx.x; e < e1; e += 256) {
    unsigned u = (unsigned)(idxarr[e] - lo);
    if (u < (unsigned)RSZ) atomicAdd(&sh[u], 1);
  }
  __syncthreads();
  int* __restrict__ part = z ? part_dst : part_src;
  const int base = (s * NR + r) * RSZ;
  for (int i = threadIdx.x; i < RSZ; i += 256) part[base + i] = sh[i];
}

// Per node: total src degree -> dis; dst partials -> in-place exclusive prefix over
// slices, total -> cnt_dst.
__global__ void __launch_bounds__(256) reduce_kernel(const int* __restrict__ part_src,
                                                     int* __restrict__ part_dst,
                                                     float* __restrict__ dis,
                                                     int* __restrict__ cnt_dst, int N) {
  int n = blockIdx.x * 256 + threadIdx.x;
  if (n >= N) return;
  int r = n / RSZ, i = n - r * RSZ;
  int ssum = 0;
  #pragma unroll 4
  for (int s = 0; s < NS; ++s) ssum += part_src[(size_t)(s * NR + r) * RSZ + i];
  dis[n] = (ssum > 0) ? rsqrtf((float)ssum) : 0.0f;
  int off = 0;
  for (int s = 0; s < NS; ++s) {
    size_t idx = (size_t)(s * NR + r) * RSZ + i;
    int c = part_dst[idx];
    part_dst[idx] = off;
    off += c;
  }
  cnt_dst[n] = off;
}

__global__ void __launch_bounds__(256) scan1_kernel(const int* __restrict__ cnt,
                                                    int* __restrict__ exc,
                                                    int* __restrict__ bsum, int N) {
  __shared__ int sh[256];
  int tid = threadIdx.x;
  int i = blockIdx.x * 256 + tid;
  int v = (i < N) ? cnt[i] : 0;
  int acc = v;
  sh[tid] = acc; __syncthreads();
  #pragma unroll
  for (int off = 1; off < 256; off <<= 1) {
    int t = (tid >= off) ? sh[tid - off] : 0;
    __syncthreads();
    acc += t;
    sh[tid] = acc;
    __syncthreads();
  }
  if (i < N) exc[i] = acc - v;
  if (tid == 255) bsum[blockIdx.x] = acc;
}

__global__ void __launch_bounds__(256) scan2_kernel(int* __restrict__ bsum, int NB) {
  __shared__ int sh[256];
  int tid = threadIdx.x;
  int v = (tid < NB) ? bsum[tid] : 0;
  int acc = v;
  sh[tid] = acc; __syncthreads();
  #pragma unroll
  for (int off = 1; off < 256; off <<= 1) {
    int t = (tid >= off) ? sh[tid - off] : 0;
    __syncthreads();
    acc += t;
    sh[tid] = acc;
    __syncthreads();
  }
  if (tid < NB) bsum[tid] = acc - v;
}

__global__ void __launch_bounds__(256) scan3_kernel(int* __restrict__ exc,
                                                    const int* __restrict__ bsum, int N) {
  int i = blockIdx.x * 256 + threadIdx.x;
  if (i < N) exc[i] += bsum[blockIdx.x];
}

// grid (NS, NR). pos = start[d] + sliceoff[s][d] + LDS-cursor rank. No global atomics.
__global__ void __launch_bounds__(256) fill_kernel(const int* __restrict__ ei, int E, int ES,
                                                   const int* __restrict__ startv,
                                                   const int* __restrict__ pd_off,
                                                   const float* __restrict__ dis,
                                                   int* __restrict__ col,
                                                   float* __restrict__ wp) {
  __shared__ int cur[RSZ];
  for (int i = threadIdx.x; i < RSZ; i += 256) cur[i] = 0;
  __syncthreads();
  const int s = blockIdx.x, r = blockIdx.y;
  const int lo = r * RSZ;
  const int base = (s * NR + r) * RSZ;
  const int e0 = s * ES, e1 = min(e0 + ES, E);
  for (int e = e0 + (int)threadIdx.x; e < e1; e += 256) {
    int sv = ei[e], d = ei[E + e];
    unsigned u = (unsigned)(d - lo);
    if (u < (unsigned)RSZ) {
      int rank = atomicAdd(&cur[u], 1);
      int pos = startv[d] + pd_off[base + u] + rank;
      col[pos] = sv;
      wp[pos] = -dis[sv] * dis[d];   // pre-negated: lap = sum(wp * v[src])
    }
  }
}

// ---------------- Fused 3-way GEMM ----------------
// A = x@W[0] - x@W[2] + b ; U = x@W[1] ; V = x@W[2]

template<int FIN, int FOUT, int RPT>
__global__ void __launch_bounds__(256) gemm3_kernel(const float* __restrict__ x,
    const float* __restrict__ W, const float* __restrict__ b,
    float* __restrict__ A, float* __restrict__ U, float* __restrict__ V, int N) {
  constexpr int TG = 256 / FOUT;
  constexpr int ROWS = TG * RPT;
  __shared__ float xs[ROWS][FIN + 4];
  const int c = threadIdx.x % FOUT;
  const int rg = threadIdx.x / FOUT;
  const int row0 = blockIdx.x * ROWS;
  for (int i = threadIdx.x * 4; i < ROWS * FIN; i += 256 * 4) {
    int r = i / FIN, k = i - r * FIN;
    float4 v = make_float4(0.f, 0.f, 0.f, 0.f);
    if (row0 + r < N) v = *(const float4*)(x + (size_t)(row0 + r) * FIN + k);
    *(float4*)(&xs[r][k]) = v;
  }
  __syncthreads();
  float acc0[RPT], acc1[RPT], acc2[RPT];
  #pragma unroll
  for (int r = 0; r < RPT; ++r) { acc0[r] = 0.f; acc1[r] = 0.f; acc2[r] = 0.f; }
  const float* W0p = W + c;
  const float* W1p = W + FIN * FOUT + c;
  const float* W2p = W + 2 * FIN * FOUT + c;
  for (int k = 0; k < FIN; ++k) {
    float w0 = W0p[k * FOUT];
    float w1 = W1p[k * FOUT];
    float w2 = W2p[k * FOUT];
    #pragma unroll
    for (int r = 0; r < RPT; ++r) {
      float xv = xs[rg * RPT + r][k];
      acc0[r] = fmaf(xv, w0, acc0[r]);
      acc1[r] = fmaf(xv, w1, acc1[r]);
      acc2[r] = fmaf(xv, w2, acc2[r]);
    }
  }
  const float bb = b[c];
  #pragma unroll
  for (int r = 0; r < RPT; ++r) {
    int row = row0 + rg * RPT + r;
    if (row < N) {
      size_t o = (size_t)row * FOUT + c;
      A[o] = acc0[r] - acc2[r] + bb;
      U[o] = acc1[r];
      V[o] = acc2[r];
    }
  }
}

// ---------------- Laplacian propagation (CSR gather, no atomics) ----------------

// Y (in U, in-place) = U + 2 * L(V): per (node,feature) owned gather-reduce.
template<int F>
__global__ void __launch_bounds__(256) lapA_kernel(const float* __restrict__ V,
    float* __restrict__ U,
    const int* __restrict__ start, const int* __restrict__ cnt,
    const int* __restrict__ col, const float* __restrict__ wp, int N) {
  int t = blockIdx.x * 256 + threadIdx.x;
  int n = t / F;
  if (n >= N) return;
  int f = t & (F - 1);
  int j = start[n], e = j + cnt[n];
  float acc = 0.f;
  for (; j + 3 < e; j += 4) {
    int s0 = col[j], s1 = col[j + 1], s2 = col[j + 2], s3 = col[j + 3];
    float w0 = wp[j], w1 = wp[j + 1], w2 = wp[j + 2], w3 = wp[j + 3];
    float v0 = V[(size_t)s0 * F + f];
    float v1 = V[(size_t)s1 * F + f];
    float v2 = V[(size_t)s2 * F + f];
    float v3 = V[(size_t)s3 * F + f];
    acc = fmaf(w0, v0, acc); acc = fmaf(w1, v1, acc);
    acc = fmaf(w2, v2, acc); acc = fmaf(w3, v3, acc);
  }
  for (; j < e; ++j)
    acc = fmaf(wp[j], V[(size_t)col[j] * F + f], acc);
  U[t] = fmaf(2.f, acc, U[t]);   // Y = U + 2*L(V), in place
}

// out = A + L(Y), optional relu.
template<int F, bool RELU>
__global__ void __launch_bounds__(256) lapB_kernel(const float* __restrict__ Y,
    const float* __restrict__ A,
    const int* __restrict__ start, const int* __restrict__ cnt,
    const int* __restrict__ col, const float* __restrict__ wp,
    float* __restrict__ out, int N) {
  int t = blockIdx.x * 256 + threadIdx.x;
  int n = t / F;
  if (n >= N) return;
  int f = t & (F - 1);
  int j = start[n], e = j + cnt[n];
  float acc = 0.f;
  for (; j + 3 < e; j += 4) {
    int s0 = col[j], s1 = col[j + 1], s2 = col[j + 2], s3 = col[j + 3];
    float w0 = wp[j], w1 = wp[j + 1], w2 = wp[j + 2], w3 = wp[j + 3];
    float v0 = Y[(size_t)s0 * F + f];
    float v1 = Y[(size_t)s1 * F + f];
    float v2 = Y[(size_t)s2 * F + f];
    float v3 = Y[(size_t)s3 * F + f];
    acc = fmaf(w0, v0, acc); acc = fmaf(w1, v1, acc);
    acc = fmaf(w2, v2, acc); acc = fmaf(w3, v3, acc);
  }
  for (; j < e; ++j)
    acc = fmaf(wp[j], Y[(size_t)col[j] * F + f], acc);
  float r = A[t] + acc;
  if (RELU) r = fmaxf(r, 0.f);
  out[t] = r;
}

// ---------------- launch ----------------

extern "C" void kernel_launch(void* const* d_in, const int* in_sizes, int n_in,
                              void* d_out, int out_size, void* d_ws, size_t ws_size,
                              hipStream_t stream) {
  const float* x  = (const float*)d_in[0];
  const int*   ei = (const int*)d_in[1];
  const float* W1 = (const float*)d_in[2];
  const float* b1 = (const float*)d_in[3];
  const float* Wm = (const float*)d_in[4];
  const float* bm = (const float*)d_in[5];
  const float* W2 = (const float*)d_in[6];
  const float* b2 = (const float*)d_in[7];
  float* out = (float*)d_out;
  const int N = NNODES;
  const int E = in_sizes[1] / 2;
  const int ES = (E + NS - 1) / NS;
  const int NB = (N + 255) / 256;  // 196

  char* p = (char*)d_ws;
  auto alloc = [&](size_t bytes) -> char* {
    char* q = p;
    p += (bytes + 255) & ~(size_t)255;
    return q;
  };
  int*   part_src = (int*)alloc((size_t)NS * NR * RSZ * 4);   // 6.4 MB
  int*   part_dst = (int*)alloc((size_t)NS * NR * RSZ * 4);   // 6.4 MB
  int*   cnt_dst  = (int*)alloc((size_t)N * 4);
  int*   startv   = (int*)alloc((size_t)N * 4);
  int*   bsum     = (int*)alloc(1024);
  float* dis      = (float*)alloc((size_t)N * 4);
  int*   col      = (int*)alloc((size_t)E * 4);
  float* wp       = (float*)alloc((size_t)E * 4);
  float* A1       = (float*)alloc((size_t)N * 64 * 4);
  float* A2       = (float*)alloc((size_t)N * 64 * 4);
  float* Ub       = (float*)alloc((size_t)N * 64 * 4);
  float* Vb       = (float*)alloc((size_t)N * 64 * 4);

  hist_kernel<<<dim3(NS, NR, 2), 256, 0, stream>>>(ei, E, ES, part_src, part_dst);
  reduce_kernel<<<NB, 256, 0, stream>>>(part_src, part_dst, dis, cnt_dst, N);
  scan1_kernel<<<NB, 256, 0, stream>>>(cnt_dst, startv, bsum, N);
  scan2_kernel<<<1, 256, 0, stream>>>(bsum, NB);
  scan3_kernel<<<NB, 256, 0, stream>>>(startv, bsum, N);
  fill_kernel<<<dim3(NS, NR), 256, 0, stream>>>(ei, E, ES, startv, part_dst, dis, col, wp);

  int gb32 = (N + 31) / 32;        // 1563
  int g64  = (N * 64 + 255) / 256; // 12500
  int g16  = (N * 16 + 255) / 256; // 3125

  // Layer 1: 128 -> 64, relu
  gemm3_kernel<128, 64, 8><<<gb32, 256, 0, stream>>>(x, W1, b1, A1, Ub, Vb, N);
  lapA_kernel<64><<<g64, 256, 0, stream>>>(Vb, Ub, startv, cnt_dst, col, wp, N);
  lapB_kernel<64, true><<<g64, 256, 0, stream>>>(Ub, A1, startv, cnt_dst, col, wp, A1, N);

  // Layer 2: 64 -> 64, relu
  gemm3_kernel<64, 64, 8><<<gb32, 256, 0, stream>>>(A1, Wm, bm, A2, Ub, Vb, N);
  lapA_kernel<64><<<g64, 256, 0, stream>>>(Vb, Ub, startv, cnt_dst, col, wp, N);
  lapB_kernel<64, true><<<g64, 256, 0, stream>>>(Ub, A2, startv, cnt_dst, col, wp, A2, N);

  // Layer 3: 64 -> 16, no relu, straight to d_out
  gemm3_kernel<64, 16, 2><<<gb32, 256, 0, stream>>>(A2, W2, b2, A1, Ub, Vb, N);
  lapA_kernel<16><<<g16, 256, 0, stream>>>(Vb, Ub, startv, cnt_dst, col, wp, N);
  lapB_kernel<16, false><<<g16, 256, 0, stream>>>(Ub, A1, startv, cnt_dst, col, wp, out, N);
}

// Round 3
// 377.619 us; speedup vs baseline: 1.3811x; 1.2326x over previous
//
#include <hip/hip_runtime.h>
#include <hip/hip_fp16.h>

constexpr int NNODES = 50000;
constexpr int NS  = 64;     // edge slices
constexpr int NR  = 4;      // node ranges
constexpr int RSZ = 12500;  // nodes per range (NR*RSZ >= NNODES)

// ---------------- CSR build: LDS partial histograms, zero global atomics ----------------

// grid (NS, NR, 2). z=0: src counts (for dis), z=1: dst counts (CSR rows).
__global__ void __launch_bounds__(256) hist_kernel(const int* __restrict__ ei, int E, int ES,
                                                   int* __restrict__ part_src,
                                                   int* __restrict__ part_dst) {
  __shared__ int sh[RSZ];
  for (int i = threadIdx.x; i < RSZ; i += 256) sh[i] = 0;
  __syncthreads();
  const int s = blockIdx.x, r = blockIdx.y, z = blockIdx.z;
  const int lo = r * RSZ;
  const int* __restrict__ idxarr = ei + (z ? E : 0);
  const int e0 = s * ES, e1 = min(e0 + ES, E);
  for (int e = e0 + (int)threadIdx.x; e < e1; e += 256) {
    unsigned u = (unsigned)(idxarr[e] - lo);
    if (u < (unsigned)RSZ) atomicAdd(&sh[u], 1);
  }
  __syncthreads();
  int* __restrict__ part = z ? part_dst : part_src;
  const int base = (s * NR + r) * RSZ;
  for (int i = threadIdx.x; i < RSZ; i += 256) part[base + i] = sh[i];
}

// Per node: total src degree -> dis; dst partials -> in-place exclusive prefix over
// slices, total -> cnt_dst.
__global__ void __launch_bounds__(256) reduce_kernel(const int* __restrict__ part_src,
                                                     int* __restrict__ part_dst,
                                                     float* __restrict__ dis,
                                                     int* __restrict__ cnt_dst, int N) {
  int n = blockIdx.x * 256 + threadIdx.x;
  if (n >= N) return;
  int r = n / RSZ, i = n - r * RSZ;
  int ssum = 0;
  #pragma unroll 4
  for (int s = 0; s < NS; ++s) ssum += part_src[(size_t)(s * NR + r) * RSZ + i];
  dis[n] = (ssum > 0) ? rsqrtf((float)ssum) : 0.0f;
  int off = 0;
  for (int s = 0; s < NS; ++s) {
    size_t idx = (size_t)(s * NR + r) * RSZ + i;
    int c = part_dst[idx];
    part_dst[idx] = off;
    off += c;
  }
  cnt_dst[n] = off;
}

__global__ void __launch_bounds__(256) scan1_kernel(const int* __restrict__ cnt,
                                                    int* __restrict__ exc,
                                                    int* __restrict__ bsum, int N) {
  __shared__ int sh[256];
  int tid = threadIdx.x;
  int i = blockIdx.x * 256 + tid;
  int v = (i < N) ? cnt[i] : 0;
  int acc = v;
  sh[tid] = acc; __syncthreads();
  #pragma unroll
  for (int off = 1; off < 256; off <<= 1) {
    int t = (tid >= off) ? sh[tid - off] : 0;
    __syncthreads();
    acc += t;
    sh[tid] = acc;
    __syncthreads();
  }
  if (i < N) exc[i] = acc - v;
  if (tid == 255) bsum[blockIdx.x] = acc;
}

__global__ void __launch_bounds__(256) scan2_kernel(int* __restrict__ bsum, int NB) {
  __shared__ int sh[256];
  int tid = threadIdx.x;
  int v = (tid < NB) ? bsum[tid] : 0;
  int acc = v;
  sh[tid] = acc; __syncthreads();
  #pragma unroll
  for (int off = 1; off < 256; off <<= 1) {
    int t = (tid >= off) ? sh[tid - off] : 0;
    __syncthreads();
    acc += t;
    sh[tid] = acc;
    __syncthreads();
  }
  if (tid < NB) bsum[tid] = acc - v;
}

__global__ void __launch_bounds__(256) scan3_kernel(int* __restrict__ exc,
                                                    const int* __restrict__ bsum, int N) {
  int i = blockIdx.x * 256 + threadIdx.x;
  if (i < N) exc[i] += bsum[blockIdx.x];
}

// grid (NS, NR). pos = start[d] + sliceoff[s][d] + LDS-cursor rank. No global atomics.
__global__ void __launch_bounds__(256) fill_kernel(const int* __restrict__ ei, int E, int ES,
                                                   const int* __restrict__ startv,
                                                   const int* __restrict__ pd_off,
                                                   const float* __restrict__ dis,
                                                   int* __restrict__ col,
                                                   float* __restrict__ wp) {
  __shared__ int cur[RSZ];
  for (int i = threadIdx.x; i < RSZ; i += 256) cur[i] = 0;
  __syncthreads();
  const int s = blockIdx.x, r = blockIdx.y;
  const int lo = r * RSZ;
  const int base = (s * NR + r) * RSZ;
  const int e0 = s * ES, e1 = min(e0 + ES, E);
  for (int e = e0 + (int)threadIdx.x; e < e1; e += 256) {
    int sv = ei[e], d = ei[E + e];
    unsigned u = (unsigned)(d - lo);
    if (u < (unsigned)RSZ) {
      int rank = atomicAdd(&cur[u], 1);
      int pos = startv[d] + pd_off[base + u] + rank;
      col[pos] = sv;
      wp[pos] = -dis[sv] * dis[d];   // pre-negated: lap = sum(wp * v[src])
    }
  }
}

// ---------------- Fused 3-way GEMM ----------------
// A = x@W[0] - x@W[2] + b ; U = x@W[1] (fp32) ; V = x@W[2] (fp16, gathered later)

template<int FIN, int FOUT, int RPT>
__global__ void __launch_bounds__(256) gemm3_kernel(const float* __restrict__ x,
    const float* __restrict__ W, const float* __restrict__ b,
    float* __restrict__ A, float* __restrict__ U, __half* __restrict__ V, int N) {
  constexpr int TG = 256 / FOUT;
  constexpr int ROWS = TG * RPT;
  __shared__ float xs[ROWS][FIN + 4];
  const int c = threadIdx.x % FOUT;
  const int rg = threadIdx.x / FOUT;
  const int row0 = blockIdx.x * ROWS;
  for (int i = threadIdx.x * 4; i < ROWS * FIN; i += 256 * 4) {
    int r = i / FIN, k = i - r * FIN;
    float4 v = make_float4(0.f, 0.f, 0.f, 0.f);
    if (row0 + r < N) v = *(const float4*)(x + (size_t)(row0 + r) * FIN + k);
    *(float4*)(&xs[r][k]) = v;
  }
  __syncthreads();
  float acc0[RPT], acc1[RPT], acc2[RPT];
  #pragma unroll
  for (int r = 0; r < RPT; ++r) { acc0[r] = 0.f; acc1[r] = 0.f; acc2[r] = 0.f; }
  const float* W0p = W + c;
  const float* W1p = W + FIN * FOUT + c;
  const float* W2p = W + 2 * FIN * FOUT + c;
  for (int k = 0; k < FIN; ++k) {
    float w0 = W0p[k * FOUT];
    float w1 = W1p[k * FOUT];
    float w2 = W2p[k * FOUT];
    #pragma unroll
    for (int r = 0; r < RPT; ++r) {
      float xv = xs[rg * RPT + r][k];
      acc0[r] = fmaf(xv, w0, acc0[r]);
      acc1[r] = fmaf(xv, w1, acc1[r]);
      acc2[r] = fmaf(xv, w2, acc2[r]);
    }
  }
  const float bb = b[c];
  #pragma unroll
  for (int r = 0; r < RPT; ++r) {
    int row = row0 + rg * RPT + r;
    if (row < N) {
      size_t o = (size_t)row * FOUT + c;
      A[o] = acc0[r] - acc2[r] + bb;
      U[o] = acc1[r];
      V[o] = __float2half(acc2[r]);
    }
  }
}

// ---------------- Laplacian propagation (CSR gather, no atomics, fp16 gathers) ----------------
// Each thread owns (node n, feature pair h): 2 features via half2.

// Yh = half(U + 2 * L(V))
template<int F>
__global__ void __launch_bounds__(256) lapA_kernel(const __half2* __restrict__ V,
    const float* __restrict__ U, __half2* __restrict__ Yh,
    const int* __restrict__ start, const int* __restrict__ cnt,
    const int* __restrict__ col, const float* __restrict__ wp, int N) {
  constexpr int H = F / 2;
  int t = blockIdx.x * 256 + threadIdx.x;
  int n = t / H;
  if (n >= N) return;
  int h = t & (H - 1);
  int j = start[n], e = j + cnt[n];
  float ax = 0.f, ay = 0.f;
  for (; j + 3 < e; j += 4) {
    int s0 = col[j], s1 = col[j + 1], s2 = col[j + 2], s3 = col[j + 3];
    float w0 = wp[j], w1 = wp[j + 1], w2 = wp[j + 2], w3 = wp[j + 3];
    float2 v0 = __half22float2(V[(size_t)s0 * H + h]);
    float2 v1 = __half22float2(V[(size_t)s1 * H + h]);
    float2 v2 = __half22float2(V[(size_t)s2 * H + h]);
    float2 v3 = __half22float2(V[(size_t)s3 * H + h]);
    ax = fmaf(w0, v0.x, ax); ay = fmaf(w0, v0.y, ay);
    ax = fmaf(w1, v1.x, ax); ay = fmaf(w1, v1.y, ay);
    ax = fmaf(w2, v2.x, ax); ay = fmaf(w2, v2.y, ay);
    ax = fmaf(w3, v3.x, ax); ay = fmaf(w3, v3.y, ay);
  }
  for (; j < e; ++j) {
    float w = wp[j];
    float2 v = __half22float2(V[(size_t)col[j] * H + h]);
    ax = fmaf(w, v.x, ax); ay = fmaf(w, v.y, ay);
  }
  float2 u = ((const float2*)U)[t];
  Yh[t] = __float22half2_rn(make_float2(fmaf(2.f, ax, u.x), fmaf(2.f, ay, u.y)));
}

// out = A + L(Y), optional relu; fp32 output.
template<int F, bool RELU>
__global__ void __launch_bounds__(256) lapB_kernel(const __half2* __restrict__ Y,
    const float* __restrict__ A,
    const int* __restrict__ start, const int* __restrict__ cnt,
    const int* __restrict__ col, const float* __restrict__ wp,
    float* __restrict__ out, int N) {
  constexpr int H = F / 2;
  int t = blockIdx.x * 256 + threadIdx.x;
  int n = t / H;
  if (n >= N) return;
  int h = t & (H - 1);
  int j = start[n], e = j + cnt[n];
  float ax = 0.f, ay = 0.f;
  for (; j + 3 < e; j += 4) {
    int s0 = col[j], s1 = col[j + 1], s2 = col[j + 2], s3 = col[j + 3];
    float w0 = wp[j], w1 = wp[j + 1], w2 = wp[j + 2], w3 = wp[j + 3];
    float2 v0 = __half22float2(Y[(size_t)s0 * H + h]);
    float2 v1 = __half22float2(Y[(size_t)s1 * H + h]);
    float2 v2 = __half22float2(Y[(size_t)s2 * H + h]);
    float2 v3 = __half22float2(Y[(size_t)s3 * H + h]);
    ax = fmaf(w0, v0.x, ax); ay = fmaf(w0, v0.y, ay);
    ax = fmaf(w1, v1.x, ax); ay = fmaf(w1, v1.y, ay);
    ax = fmaf(w2, v2.x, ax); ay = fmaf(w2, v2.y, ay);
    ax = fmaf(w3, v3.x, ax); ay = fmaf(w3, v3.y, ay);
  }
  for (; j < e; ++j) {
    float w = wp[j];
    float2 v = __half22float2(Y[(size_t)col[j] * H + h]);
    ax = fmaf(w, v.x, ax); ay = fmaf(w, v.y, ay);
  }
  float2 a = ((const float2*)A)[t];
  float rx = a.x + ax, ry = a.y + ay;
  if (RELU) { rx = fmaxf(rx, 0.f); ry = fmaxf(ry, 0.f); }
  ((float2*)out)[t] = make_float2(rx, ry);
}

// ---------------- launch ----------------

extern "C" void kernel_launch(void* const* d_in, const int* in_sizes, int n_in,
                              void* d_out, int out_size, void* d_ws, size_t ws_size,
                              hipStream_t stream) {
  const float* x  = (const float*)d_in[0];
  const int*   ei = (const int*)d_in[1];
  const float* W1 = (const float*)d_in[2];
  const float* b1 = (const float*)d_in[3];
  const float* Wm = (const float*)d_in[4];
  const float* bm = (const float*)d_in[5];
  const float* W2 = (const float*)d_in[6];
  const float* b2 = (const float*)d_in[7];
  float* out = (float*)d_out;
  const int N = NNODES;
  const int E = in_sizes[1] / 2;
  const int ES = (E + NS - 1) / NS;
  const int NB = (N + 255) / 256;  // 196

  char* p = (char*)d_ws;
  auto alloc = [&](size_t bytes) -> char* {
    char* q = p;
    p += (bytes + 255) & ~(size_t)255;
    return q;
  };
  int*    part_src = (int*)alloc((size_t)NS * NR * RSZ * 4);   // 12.8 MB
  int*    part_dst = (int*)alloc((size_t)NS * NR * RSZ * 4);   // 12.8 MB
  int*    cnt_dst  = (int*)alloc((size_t)N * 4);
  int*    startv   = (int*)alloc((size_t)N * 4);
  int*    bsum     = (int*)alloc(1024);
  float*  dis      = (float*)alloc((size_t)N * 4);
  int*    col      = (int*)alloc((size_t)E * 4);
  float*  wp       = (float*)alloc((size_t)E * 4);
  float*  A1       = (float*)alloc((size_t)N * 64 * 4);
  float*  A2       = (float*)alloc((size_t)N * 64 * 4);
  float*  Ub       = (float*)alloc((size_t)N * 64 * 4);
  __half* Vh       = (__half*)alloc((size_t)N * 64 * 2);
  __half* Yh       = (__half*)alloc((size_t)N * 64 * 2);

  hist_kernel<<<dim3(NS, NR, 2), 256, 0, stream>>>(ei, E, ES, part_src, part_dst);
  reduce_kernel<<<NB, 256, 0, stream>>>(part_src, part_dst, dis, cnt_dst, N);
  scan1_kernel<<<NB, 256, 0, stream>>>(cnt_dst, startv, bsum, N);
  scan2_kernel<<<1, 256, 0, stream>>>(bsum, NB);
  scan3_kernel<<<NB, 256, 0, stream>>>(startv, bsum, N);
  fill_kernel<<<dim3(NS, NR), 256, 0, stream>>>(ei, E, ES, startv, part_dst, dis, col, wp);

  int gb32 = (N + 31) / 32;          // 1563
  int g64h = (N * 32 + 255) / 256;   // 6250  (F=64, half2 threads)
  int g16h = (N * 8  + 255) / 256;   // 1563  (F=16, half2 threads)

  // Layer 1: 128 -> 64, relu
  gemm3_kernel<128, 64, 8><<<gb32, 256, 0, stream>>>(x, W1, b1, A1, Ub, Vh, N);
  lapA_kernel<64><<<g64h, 256, 0, stream>>>((const __half2*)Vh, Ub, (__half2*)Yh, startv, cnt_dst, col, wp, N);
  lapB_kernel<64, true><<<g64h, 256, 0, stream>>>((const __half2*)Yh, A1, startv, cnt_dst, col, wp, A1, N);

  // Layer 2: 64 -> 64, relu
  gemm3_kernel<64, 64, 8><<<gb32, 256, 0, stream>>>(A1, Wm, bm, A2, Ub, Vh, N);
  lapA_kernel<64><<<g64h, 256, 0, stream>>>((const __half2*)Vh, Ub, (__half2*)Yh, startv, cnt_dst, col, wp, N);
  lapB_kernel<64, true><<<g64h, 256, 0, stream>>>((const __half2*)Yh, A2, startv, cnt_dst, col, wp, A2, N);

  // Layer 3: 64 -> 16, no relu, straight to d_out
  gemm3_kernel<64, 16, 2><<<gb32, 256, 0, stream>>>(A2, W2, b2, A1, Ub, Vh, N);
  lapA_kernel<16><<<g16h, 256, 0, stream>>>((const __half2*)Vh, Ub, (__half2*)Yh, startv, cnt_dst, col, wp, N);
  lapB_kernel<16, false><<<g16h, 256, 0, stream>>>((const __half2*)Yh, A1, startv, cnt_dst, col, wp, out, N);
}

// Round 4
// 316.906 us; speedup vs baseline: 1.6457x; 1.1916x over previous
//
#include <hip/hip_runtime.h>
#include <hip/hip_fp16.h>

constexpr int NNODES = 50000;
constexpr int NS  = 64;     // edge slices
constexpr int NR  = 4;      // node ranges
constexpr int RSZ = 12500;  // nodes per range (NR*RSZ >= NNODES)

typedef _Float16 half8_t __attribute__((ext_vector_type(8)));
typedef float    f32x4_t __attribute__((ext_vector_type(4)));

// ---------------- CSR build: LDS partial histograms, zero global atomics ----------------

__global__ void __launch_bounds__(256) hist_kernel(const int* __restrict__ ei, int E, int ES,
                                                   int* __restrict__ part_src,
                                                   int* __restrict__ part_dst) {
  __shared__ int sh[RSZ];
  for (int i = threadIdx.x; i < RSZ; i += 256) sh[i] = 0;
  __syncthreads();
  const int s = blockIdx.x, r = blockIdx.y, z = blockIdx.z;
  const int lo = r * RSZ;
  const int* __restrict__ idxarr = ei + (z ? E : 0);
  const int e0 = s * ES, e1 = min(e0 + ES, E);
  for (int e = e0 + (int)threadIdx.x; e < e1; e += 256) {
    unsigned u = (unsigned)(idxarr[e] - lo);
    if (u < (unsigned)RSZ) atomicAdd(&sh[u], 1);
  }
  __syncthreads();
  int* __restrict__ part = z ? part_dst : part_src;
  const int base = (s * NR + r) * RSZ;
  for (int i = threadIdx.x; i < RSZ; i += 256) part[base + i] = sh[i];
}

__global__ void __launch_bounds__(256) reduce_kernel(const int* __restrict__ part_src,
                                                     int* __restrict__ part_dst,
                                                     float* __restrict__ dis,
                                                     int* __restrict__ cnt_dst, int N) {
  int n = blockIdx.x * 256 + threadIdx.x;
  if (n >= N) return;
  int r = n / RSZ, i = n - r * RSZ;
  int ssum = 0;
  #pragma unroll 4
  for (int s = 0; s < NS; ++s) ssum += part_src[(size_t)(s * NR + r) * RSZ + i];
  dis[n] = (ssum > 0) ? rsqrtf((float)ssum) : 0.0f;
  int off = 0;
  for (int s = 0; s < NS; ++s) {
    size_t idx = (size_t)(s * NR + r) * RSZ + i;
    int c = part_dst[idx];
    part_dst[idx] = off;
    off += c;
  }
  cnt_dst[n] = off;
}

__global__ void __launch_bounds__(256) scan1_kernel(const int* __restrict__ cnt,
                                                    int* __restrict__ exc,
                                                    int* __restrict__ bsum, int N) {
  __shared__ int sh[256];
  int tid = threadIdx.x;
  int i = blockIdx.x * 256 + tid;
  int v = (i < N) ? cnt[i] : 0;
  int acc = v;
  sh[tid] = acc; __syncthreads();
  #pragma unroll
  for (int off = 1; off < 256; off <<= 1) {
    int t = (tid >= off) ? sh[tid - off] : 0;
    __syncthreads();
    acc += t;
    sh[tid] = acc;
    __syncthreads();
  }
  if (i < N) exc[i] = acc - v;
  if (tid == 255) bsum[blockIdx.x] = acc;
}

__global__ void __launch_bounds__(256) scan2_kernel(int* __restrict__ bsum, int NB) {
  __shared__ int sh[256];
  int tid = threadIdx.x;
  int v = (tid < NB) ? bsum[tid] : 0;
  int acc = v;
  sh[tid] = acc; __syncthreads();
  #pragma unroll
  for (int off = 1; off < 256; off <<= 1) {
    int t = (tid >= off) ? sh[tid - off] : 0;
    __syncthreads();
    acc += t;
    sh[tid] = acc;
    __syncthreads();
  }
  if (tid < NB) bsum[tid] = acc - v;
}

__global__ void __launch_bounds__(256) scan3_kernel(int* __restrict__ exc,
                                                    const int* __restrict__ bsum, int N) {
  int i = blockIdx.x * 256 + threadIdx.x;
  if (i < N) exc[i] += bsum[blockIdx.x];
}

// grid (NS, NR). pos = start[d] + sliceoff[s][d] + LDS-cursor rank. No global atomics.
// Writes paired (col, weight) as one int2 -> one write-allocated line per edge.
__global__ void __launch_bounds__(256) fill_kernel(const int* __restrict__ ei, int E, int ES,
                                                   const int* __restrict__ startv,
                                                   const int* __restrict__ pd_off,
                                                   const float* __restrict__ dis,
                                                   int2* __restrict__ ew) {
  __shared__ int cur[RSZ];
  for (int i = threadIdx.x; i < RSZ; i += 256) cur[i] = 0;
  __syncthreads();
  const int s = blockIdx.x, r = blockIdx.y;
  const int lo = r * RSZ;
  const int base = (s * NR + r) * RSZ;
  const int e0 = s * ES, e1 = min(e0 + ES, E);
  for (int e = e0 + (int)threadIdx.x; e < e1; e += 256) {
    int sv = ei[e], d = ei[E + e];
    unsigned u = (unsigned)(d - lo);
    if (u < (unsigned)RSZ) {
      int rank = atomicAdd(&cur[u], 1);
      int pos = startv[d] + pd_off[base + u] + rank;
      float w = -dis[sv] * dis[d];   // pre-negated: lap = sum(w * v[src])
      ew[pos] = make_int2(sv, __float_as_int(w));
    }
  }
}

// ---------------- Weight packing into MFMA B-fragment order ----------------
// B-frag (16x16x32 f16): lane holds B[k = (lane>>4)*8 + j][n = lane&15], j=0..7.
// Bp element index: ((kt*NT + nt)*64 + lane)*8 + j ; n_global = nt*16 + (lane&15),
// cheb = n/FOUT, c = n%FOUT, k = kt*32 + (lane>>4)*8 + j.
template<int FIN, int FOUT>
__global__ void __launch_bounds__(256) pack_kernel(const float* __restrict__ W,
                                                   _Float16* __restrict__ Bp) {
  constexpr int NT = 3 * FOUT / 16;
  constexpr int KT = FIN / 32;
  const int total = KT * NT * 512;
  for (int i = blockIdx.x * 256 + threadIdx.x; i < total; i += gridDim.x * 256) {
    int j = i & 7;
    int lane = (i >> 3) & 63;
    int tile = i >> 9;
    int nt = tile % NT, kt = tile / NT;
    int k = kt * 32 + (lane >> 4) * 8 + j;
    int n = nt * 16 + (lane & 15);
    int cheb = n / FOUT, c = n - cheb * FOUT;
    Bp[i] = (_Float16)W[((size_t)cheb * FIN + k) * FOUT + c];
  }
}

// ---------------- MFMA fused 3-way GEMM ----------------
// D = X @ [W0 | W1 | W2]  (M x 3*FOUT). Epilogue: A = D0 - D2 + b ; U = D1 ; V = D2.
// All outputs fp16. Block = 4 waves, 64 rows; wave w owns rows w*16..w*16+15.

template<int FIN, int FOUT, typename IN_T>
__global__ void __launch_bounds__(256) gemm_mfma_kernel(const IN_T* __restrict__ X,
    const _Float16* __restrict__ Bp, const float* __restrict__ b,
    _Float16* __restrict__ A, _Float16* __restrict__ U, _Float16* __restrict__ V, int N) {
  constexpr int NT = 3 * FOUT / 16;   // 12 (FOUT=64) or 3 (FOUT=16)
  constexpr int C3 = NT / 3;          // tiles per cheb slab
  constexpr int KT = FIN / 32;
  constexpr int LDR = FIN + 8;        // pad 16B: row stride 272B/144B -> 2-way LDS alias (free)
  __shared__ _Float16 xs[64 * LDR];

  const int tid = threadIdx.x;
  const int row0 = blockIdx.x * 64;

  // Stage 64 x FIN into LDS as fp16 (coalesced global reads).
  for (int i = tid * 4; i < 64 * FIN; i += 1024) {
    int r = i / FIN, k = i - r * FIN;
    int row = row0 + r;
    short4 hv = make_short4(0, 0, 0, 0);
    if (row < N) {
      if constexpr (sizeof(IN_T) == 4) {
        float4 v = *(const float4*)((const float*)X + (size_t)row * FIN + k);
        _Float16 h0 = (_Float16)v.x, h1 = (_Float16)v.y, h2 = (_Float16)v.z, h3 = (_Float16)v.w;
        hv = make_short4(*(short*)&h0, *(short*)&h1, *(short*)&h2, *(short*)&h3);
      } else {
        hv = *(const short4*)((const _Float16*)X + (size_t)row * FIN + k);
      }
    }
    *(short4*)(&xs[r * LDR + k]) = hv;
  }
  __syncthreads();

  const int wave = tid >> 6, lane = tid & 63;
  const int m = lane & 15, quad = lane >> 4;

  f32x4_t acc[NT];
  #pragma unroll
  for (int nt = 0; nt < NT; ++nt) acc[nt] = (f32x4_t){0.f, 0.f, 0.f, 0.f};

  #pragma unroll
  for (int kt = 0; kt < KT; ++kt) {
    half8_t a = *(const half8_t*)(&xs[(wave * 16 + m) * LDR + kt * 32 + quad * 8]);
    const half8_t* bp = (const half8_t*)Bp + (size_t)(kt * NT) * 64 + lane;
    #pragma unroll
    for (int nt = 0; nt < NT; ++nt) {
      half8_t bf = bp[(size_t)nt * 64];
      acc[nt] = __builtin_amdgcn_mfma_f32_16x16x32_f16(a, bf, acc[nt], 0, 0, 0);
    }
  }

  // Epilogue. C/D: col = lane&15, row = quad*4 + reg.
  const int row_b = row0 + wave * 16 + quad * 4;
  #pragma unroll
  for (int nt = 0; nt < C3; ++nt) {
    int c = nt * 16 + m;
    float bb = b[c];
    #pragma unroll
    for (int r = 0; r < 4; ++r) {
      int row = row_b + r;
      if (row < N) {
        size_t o = (size_t)row * FOUT + c;
        A[o] = (_Float16)(acc[nt][r] - acc[nt + 2 * C3][r] + bb);
        U[o] = (_Float16)acc[nt + C3][r];
        V[o] = (_Float16)acc[nt + 2 * C3][r];
      }
    }
  }
}

// ---------------- Laplacian propagation (CSR gather, fp16, paired edges) ----------------
// Thread owns (node n, feature-pair h).

// Yh = half(U + 2 * L(V))
template<int F>
__global__ void __launch_bounds__(256) lapA_kernel(const __half2* __restrict__ V,
    const __half2* __restrict__ Uh, __half2* __restrict__ Yh,
    const int* __restrict__ start, const int* __restrict__ cnt,
    const int2* __restrict__ ew, int N) {
  constexpr int H = F / 2;
  int t = blockIdx.x * 256 + threadIdx.x;
  int n = t / H;
  if (n >= N) return;
  int h = t & (H - 1);
  int j = start[n], e = j + cnt[n];
  float ax = 0.f, ay = 0.f;
  for (; j + 3 < e; j += 4) {
    int2 c0 = ew[j], c1 = ew[j + 1], c2 = ew[j + 2], c3 = ew[j + 3];
    float2 v0 = __half22float2(V[(size_t)c0.x * H + h]);
    float2 v1 = __half22float2(V[(size_t)c1.x * H + h]);
    float2 v2 = __half22float2(V[(size_t)c2.x * H + h]);
    float2 v3 = __half22float2(V[(size_t)c3.x * H + h]);
    float w0 = __int_as_float(c0.y), w1 = __int_as_float(c1.y);
    float w2 = __int_as_float(c2.y), w3 = __int_as_float(c3.y);
    ax = fmaf(w0, v0.x, ax); ay = fmaf(w0, v0.y, ay);
    ax = fmaf(w1, v1.x, ax); ay = fmaf(w1, v1.y, ay);
    ax = fmaf(w2, v2.x, ax); ay = fmaf(w2, v2.y, ay);
    ax = fmaf(w3, v3.x, ax); ay = fmaf(w3, v3.y, ay);
  }
  for (; j < e; ++j) {
    int2 c = ew[j];
    float w = __int_as_float(c.y);
    float2 v = __half22float2(V[(size_t)c.x * H + h]);
    ax = fmaf(w, v.x, ax); ay = fmaf(w, v.y, ay);
  }
  float2 u = __half22float2(Uh[t]);
  Yh[t] = __float22half2_rn(make_float2(fmaf(2.f, ax, u.x), fmaf(2.f, ay, u.y)));
}

// out = A + L(Y) (+relu). OUT32: fp32 float2 (final layer) else fp16 half2.
template<int F, bool RELU, bool OUT32>
__global__ void __launch_bounds__(256) lapB_kernel(const __half2* __restrict__ Y,
    const __half2* __restrict__ Ah,
    const int* __restrict__ start, const int* __restrict__ cnt,
    const int2* __restrict__ ew, void* __restrict__ outp, int N) {
  constexpr int H = F / 2;
  int t = blockIdx.x * 256 + threadIdx.x;
  int n = t / H;
  if (n >= N) return;
  int h = t & (H - 1);
  int j = start[n], e = j + cnt[n];
  float ax = 0.f, ay = 0.f;
  for (; j + 3 < e; j += 4) {
    int2 c0 = ew[j], c1 = ew[j + 1], c2 = ew[j + 2], c3 = ew[j + 3];
    float2 v0 = __half22float2(Y[(size_t)c0.x * H + h]);
    float2 v1 = __half22float2(Y[(size_t)c1.x * H + h]);
    float2 v2 = __half22float2(Y[(size_t)c2.x * H + h]);
    float2 v3 = __half22float2(Y[(size_t)c3.x * H + h]);
    float w0 = __int_as_float(c0.y), w1 = __int_as_float(c1.y);
    float w2 = __int_as_float(c2.y), w3 = __int_as_float(c3.y);
    ax = fmaf(w0, v0.x, ax); ay = fmaf(w0, v0.y, ay);
    ax = fmaf(w1, v1.x, ax); ay = fmaf(w1, v1.y, ay);
    ax = fmaf(w2, v2.x, ax); ay = fmaf(w2, v2.y, ay);
    ax = fmaf(w3, v3.x, ax); ay = fmaf(w3, v3.y, ay);
  }
  for (; j < e; ++j) {
    int2 c = ew[j];
    float w = __int_as_float(c.y);
    float2 v = __half22float2(Y[(size_t)c.x * H + h]);
    ax = fmaf(w, v.x, ax); ay = fmaf(w, v.y, ay);
  }
  float2 a = __half22float2(Ah[t]);
  float rx = a.x + ax, ry = a.y + ay;
  if (RELU) { rx = fmaxf(rx, 0.f); ry = fmaxf(ry, 0.f); }
  if (OUT32) ((float2*)outp)[t] = make_float2(rx, ry);
  else       ((__half2*)outp)[t] = __float22half2_rn(make_float2(rx, ry));
}

// ---------------- launch ----------------

extern "C" void kernel_launch(void* const* d_in, const int* in_sizes, int n_in,
                              void* d_out, int out_size, void* d_ws, size_t ws_size,
                              hipStream_t stream) {
  const float* x  = (const float*)d_in[0];
  const int*   ei = (const int*)d_in[1];
  const float* W1 = (const float*)d_in[2];
  const float* b1 = (const float*)d_in[3];
  const float* Wm = (const float*)d_in[4];
  const float* bm = (const float*)d_in[5];
  const float* W2 = (const float*)d_in[6];
  const float* b2 = (const float*)d_in[7];
  float* out = (float*)d_out;
  const int N = NNODES;
  const int E = in_sizes[1] / 2;
  const int ES = (E + NS - 1) / NS;
  const int NB = (N + 255) / 256;  // 196

  char* p = (char*)d_ws;
  auto alloc = [&](size_t bytes) -> char* {
    char* q = p;
    p += (bytes + 255) & ~(size_t)255;
    return q;
  };
  int*      part_src = (int*)alloc((size_t)NS * NR * RSZ * 4);   // 12.8 MB
  int*      part_dst = (int*)alloc((size_t)NS * NR * RSZ * 4);   // 12.8 MB
  int*      cnt_dst  = (int*)alloc((size_t)N * 4);
  int*      startv   = (int*)alloc((size_t)N * 4);
  int*      bsum     = (int*)alloc(1024);
  float*    dis      = (float*)alloc((size_t)N * 4);
  int2*     ew       = (int2*)alloc((size_t)E * 8);              // 6.4 MB
  _Float16* Xh       = (_Float16*)alloc((size_t)N * 64 * 2);
  _Float16* Ah       = (_Float16*)alloc((size_t)N * 64 * 2);
  _Float16* Uh       = (_Float16*)alloc((size_t)N * 64 * 2);
  _Float16* Vh       = (_Float16*)alloc((size_t)N * 64 * 2);
  _Float16* Yh       = (_Float16*)alloc((size_t)N * 64 * 2);
  _Float16* Bp1      = (_Float16*)alloc((size_t)128 * 192 * 2);
  _Float16* Bp2      = (_Float16*)alloc((size_t)64 * 192 * 2);
  _Float16* Bp3      = (_Float16*)alloc((size_t)64 * 48 * 2);

  // CSR build
  hist_kernel<<<dim3(NS, NR, 2), 256, 0, stream>>>(ei, E, ES, part_src, part_dst);
  reduce_kernel<<<NB, 256, 0, stream>>>(part_src, part_dst, dis, cnt_dst, N);
  scan1_kernel<<<NB, 256, 0, stream>>>(cnt_dst, startv, bsum, N);
  scan2_kernel<<<1, 256, 0, stream>>>(bsum, NB);
  scan3_kernel<<<NB, 256, 0, stream>>>(startv, bsum, N);
  fill_kernel<<<dim3(NS, NR), 256, 0, stream>>>(ei, E, ES, startv, part_dst, dis, ew);

  // Weight packs (tiny; overlap with CSR build is fine — independent)
  pack_kernel<128, 64><<<24, 256, 0, stream>>>(W1, Bp1);
  pack_kernel<64, 64><<<12, 256, 0, stream>>>(Wm, Bp2);
  pack_kernel<64, 16><<<3, 256, 0, stream>>>(W2, Bp3);

  const int gmm = (N + 63) / 64;     // 782
  const int g64h = (N * 32 + 255) / 256;   // 6250
  const int g16h = (N * 8 + 255) / 256;    // 1563

  // Layer 1: 128 -> 64, relu
  gemm_mfma_kernel<128, 64, float><<<gmm, 256, 0, stream>>>(x, Bp1, b1, Ah, Uh, Vh, N);
  lapA_kernel<64><<<g64h, 256, 0, stream>>>((const __half2*)Vh, (const __half2*)Uh,
                                            (__half2*)Yh, startv, cnt_dst, ew, N);
  lapB_kernel<64, true, false><<<g64h, 256, 0, stream>>>((const __half2*)Yh, (const __half2*)Ah,
                                                         startv, cnt_dst, ew, Xh, N);

  // Layer 2: 64 -> 64, relu
  gemm_mfma_kernel<64, 64, _Float16><<<gmm, 256, 0, stream>>>(Xh, Bp2, bm, Ah, Uh, Vh, N);
  lapA_kernel<64><<<g64h, 256, 0, stream>>>((const __half2*)Vh, (const __half2*)Uh,
                                            (__half2*)Yh, startv, cnt_dst, ew, N);
  lapB_kernel<64, true, false><<<g64h, 256, 0, stream>>>((const __half2*)Yh, (const __half2*)Ah,
                                                         startv, cnt_dst, ew, Xh, N);

  // Layer 3: 64 -> 16, no relu, fp32 out
  gemm_mfma_kernel<64, 16, _Float16><<<gmm, 256, 0, stream>>>(Xh, Bp3, b2, Ah, Uh, Vh, N);
  lapA_kernel<16><<<g16h, 256, 0, stream>>>((const __half2*)Vh, (const __half2*)Uh,
                                            (__half2*)Yh, startv, cnt_dst, ew, N);
  lapB_kernel<16, false, true><<<g16h, 256, 0, stream>>>((const __half2*)Yh, (const __half2*)Ah,
                                                         startv, cnt_dst, ew, out, N);
}

// Round 5
// 288.412 us; speedup vs baseline: 1.8083x; 1.0988x over previous
//
#include <hip/hip_runtime.h>
#include <hip/hip_fp16.h>

constexpr int NNODES = 50000;
constexpr int NS  = 64;     // edge slices
constexpr int NR  = 4;      // node ranges
constexpr int RSZ = 12500;  // nodes per range (NR*RSZ >= NNODES)

typedef _Float16 half8_t __attribute__((ext_vector_type(8)));
typedef _Float16 half4_t __attribute__((ext_vector_type(4)));
typedef float    f32x4_t __attribute__((ext_vector_type(4)));

template<int CH> struct hvec_sel;
template<> struct hvec_sel<4> { using T = half4_t; };
template<> struct hvec_sel<8> { using T = half8_t; };

// ---------------- CSR build: LDS partial histograms, zero global atomics ----------------

__global__ void __launch_bounds__(256) hist_kernel(const int* __restrict__ ei, int E, int ES,
                                                   int* __restrict__ part_src,
                                                   int* __restrict__ part_dst) {
  __shared__ int sh[RSZ];
  for (int i = threadIdx.x; i < RSZ; i += 256) sh[i] = 0;
  __syncthreads();
  const int s = blockIdx.x, r = blockIdx.y, z = blockIdx.z;
  const int lo = r * RSZ;
  const int* __restrict__ idxarr = ei + (z ? E : 0);
  const int e0 = s * ES, e1 = min(e0 + ES, E);
  for (int e = e0 + (int)threadIdx.x; e < e1; e += 256) {
    unsigned u = (unsigned)(idxarr[e] - lo);
    if (u < (unsigned)RSZ) atomicAdd(&sh[u], 1);
  }
  __syncthreads();
  int* __restrict__ part = z ? part_dst : part_src;
  const int base = (s * NR + r) * RSZ;
  for (int i = threadIdx.x; i < RSZ; i += 256) part[base + i] = sh[i];
}

__global__ void __launch_bounds__(256) reduce_kernel(const int* __restrict__ part_src,
                                                     int* __restrict__ part_dst,
                                                     float* __restrict__ dis,
                                                     int* __restrict__ cnt_dst, int N) {
  int n = blockIdx.x * 256 + threadIdx.x;
  if (n >= N) return;
  int r = n / RSZ, i = n - r * RSZ;
  int ssum = 0;
  #pragma unroll 4
  for (int s = 0; s < NS; ++s) ssum += part_src[(size_t)(s * NR + r) * RSZ + i];
  dis[n] = (ssum > 0) ? rsqrtf((float)ssum) : 0.0f;
  int off = 0;
  for (int s = 0; s < NS; ++s) {
    size_t idx = (size_t)(s * NR + r) * RSZ + i;
    int c = part_dst[idx];
    part_dst[idx] = off;
    off += c;
  }
  cnt_dst[n] = off;
}

__global__ void __launch_bounds__(256) scan1_kernel(const int* __restrict__ cnt,
                                                    int* __restrict__ exc,
                                                    int* __restrict__ bsum, int N) {
  __shared__ int sh[256];
  int tid = threadIdx.x;
  int i = blockIdx.x * 256 + tid;
  int v = (i < N) ? cnt[i] : 0;
  int acc = v;
  sh[tid] = acc; __syncthreads();
  #pragma unroll
  for (int off = 1; off < 256; off <<= 1) {
    int t = (tid >= off) ? sh[tid - off] : 0;
    __syncthreads();
    acc += t;
    sh[tid] = acc;
    __syncthreads();
  }
  if (i < N) exc[i] = acc - v;
  if (tid == 255) bsum[blockIdx.x] = acc;
}

__global__ void __launch_bounds__(256) scan2_kernel(int* __restrict__ bsum, int NB) {
  __shared__ int sh[256];
  int tid = threadIdx.x;
  int v = (tid < NB) ? bsum[tid] : 0;
  int acc = v;
  sh[tid] = acc; __syncthreads();
  #pragma unroll
  for (int off = 1; off < 256; off <<= 1) {
    int t = (tid >= off) ? sh[tid - off] : 0;
    __syncthreads();
    acc += t;
    sh[tid] = acc;
    __syncthreads();
  }
  if (tid < NB) bsum[tid] = acc - v;
}

__global__ void __launch_bounds__(256) scan3_kernel(int* __restrict__ exc,
                                                    const int* __restrict__ bsum, int N) {
  int i = blockIdx.x * 256 + threadIdx.x;
  if (i < N) exc[i] += bsum[blockIdx.x];
}

// grid (NS, NR). pos = start[d] + sliceoff[s][d] + LDS-cursor rank. No global atomics.
__global__ void __launch_bounds__(256) fill_kernel(const int* __restrict__ ei, int E, int ES,
                                                   const int* __restrict__ startv,
                                                   const int* __restrict__ pd_off,
                                                   const float* __restrict__ dis,
                                                   int2* __restrict__ ew) {
  __shared__ int cur[RSZ];
  for (int i = threadIdx.x; i < RSZ; i += 256) cur[i] = 0;
  __syncthreads();
  const int s = blockIdx.x, r = blockIdx.y;
  const int lo = r * RSZ;
  const int base = (s * NR + r) * RSZ;
  const int e0 = s * ES, e1 = min(e0 + ES, E);
  for (int e = e0 + (int)threadIdx.x; e < e1; e += 256) {
    int sv = ei[e], d = ei[E + e];
    unsigned u = (unsigned)(d - lo);
    if (u < (unsigned)RSZ) {
      int rank = atomicAdd(&cur[u], 1);
      int pos = startv[d] + pd_off[base + u] + rank;
      float w = -dis[sv] * dis[d];   // pre-negated: lap = sum(w * v[src])
      ew[pos] = make_int2(sv, __float_as_int(w));
    }
  }
}

// ---------------- Weight packing into MFMA B-fragment order ----------------
template<int FIN, int FOUT>
__global__ void __launch_bounds__(256) pack_kernel(const float* __restrict__ W,
                                                   _Float16* __restrict__ Bp) {
  constexpr int NT = 3 * FOUT / 16;
  constexpr int KT = FIN / 32;
  const int total = KT * NT * 512;
  for (int i = blockIdx.x * 256 + threadIdx.x; i < total; i += gridDim.x * 256) {
    int j = i & 7;
    int lane = (i >> 3) & 63;
    int tile = i >> 9;
    int nt = tile % NT, kt = tile / NT;
    int k = kt * 32 + (lane >> 4) * 8 + j;
    int n = nt * 16 + (lane & 15);
    int cheb = n / FOUT, c = n - cheb * FOUT;
    Bp[i] = (_Float16)W[((size_t)cheb * FIN + k) * FOUT + c];
  }
}

// ---------------- MFMA fused 3-way GEMM ----------------
// D = X @ [W0 | W1 | W2]. Epilogue: A = D0 - D2 + b ; U = D1 ; V = D2 (all fp16).
template<int FIN, int FOUT, typename IN_T>
__global__ void __launch_bounds__(256) gemm_mfma_kernel(const IN_T* __restrict__ X,
    const _Float16* __restrict__ Bp, const float* __restrict__ b,
    _Float16* __restrict__ A, _Float16* __restrict__ U, _Float16* __restrict__ V, int N) {
  constexpr int NT = 3 * FOUT / 16;
  constexpr int C3 = NT / 3;
  constexpr int KT = FIN / 32;
  constexpr int LDR = FIN + 8;
  __shared__ _Float16 xs[64 * LDR];

  const int tid = threadIdx.x;
  const int row0 = blockIdx.x * 64;

  for (int i = tid * 4; i < 64 * FIN; i += 1024) {
    int r = i / FIN, k = i - r * FIN;
    int row = row0 + r;
    short4 hv = make_short4(0, 0, 0, 0);
    if (row < N) {
      if constexpr (sizeof(IN_T) == 4) {
        float4 v = *(const float4*)((const float*)X + (size_t)row * FIN + k);
        _Float16 h0 = (_Float16)v.x, h1 = (_Float16)v.y, h2 = (_Float16)v.z, h3 = (_Float16)v.w;
        hv = make_short4(*(short*)&h0, *(short*)&h1, *(short*)&h2, *(short*)&h3);
      } else {
        hv = *(const short4*)((const _Float16*)X + (size_t)row * FIN + k);
      }
    }
    *(short4*)(&xs[r * LDR + k]) = hv;
  }
  __syncthreads();

  const int wave = tid >> 6, lane = tid & 63;
  const int m = lane & 15, quad = lane >> 4;

  f32x4_t acc[NT];
  #pragma unroll
  for (int nt = 0; nt < NT; ++nt) acc[nt] = (f32x4_t){0.f, 0.f, 0.f, 0.f};

  #pragma unroll
  for (int kt = 0; kt < KT; ++kt) {
    half8_t a = *(const half8_t*)(&xs[(wave * 16 + m) * LDR + kt * 32 + quad * 8]);
    const half8_t* bp = (const half8_t*)Bp + (size_t)(kt * NT) * 64 + lane;
    #pragma unroll
    for (int nt = 0; nt < NT; ++nt) {
      half8_t bf = bp[(size_t)nt * 64];
      acc[nt] = __builtin_amdgcn_mfma_f32_16x16x32_f16(a, bf, acc[nt], 0, 0, 0);
    }
  }

  const int row_b = row0 + wave * 16 + quad * 4;
  #pragma unroll
  for (int nt = 0; nt < C3; ++nt) {
    int c = nt * 16 + m;
    float bb = b[c];
    #pragma unroll
    for (int r = 0; r < 4; ++r) {
      int row = row_b + r;
      if (row < N) {
        size_t o = (size_t)row * FOUT + c;
        A[o] = (_Float16)(acc[nt][r] - acc[nt + 2 * C3][r] + bb);
        U[o] = (_Float16)acc[nt + C3][r];
        V[o] = (_Float16)acc[nt + 2 * C3][r];
      }
    }
  }
}

// ---------------- Laplacian propagation (CSR gather, wide fp16 chunks) ----------------
// Thread owns (node n, CH-feature chunk h). CH=8 -> 16B gathers (F=64), CH=4 -> 8B (F=16).

// Y = half(U + 2 * L(V))
template<int F, int CH>
__global__ void __launch_bounds__(256) lapA_kernel(const void* __restrict__ Vp,
    const void* __restrict__ Up, void* __restrict__ Yp,
    const int* __restrict__ start, const int* __restrict__ cnt,
    const int2* __restrict__ ew, int N) {
  using HT = typename hvec_sel<CH>::T;
  constexpr int H = F / CH;
  const HT* __restrict__ Vv = (const HT*)Vp;
  int t = blockIdx.x * 256 + threadIdx.x;
  int n = t / H;
  if (n >= N) return;
  int h = t - n * H;
  int j = start[n], e = j + cnt[n];
  float acc[CH];
  #pragma unroll
  for (int i = 0; i < CH; ++i) acc[i] = 0.f;
  for (; j + 3 < e; j += 4) {
    int2 cc0 = ew[j], cc1 = ew[j + 1], cc2 = ew[j + 2], cc3 = ew[j + 3];
    HT v0 = Vv[(size_t)cc0.x * H + h];
    HT v1 = Vv[(size_t)cc1.x * H + h];
    HT v2 = Vv[(size_t)cc2.x * H + h];
    HT v3 = Vv[(size_t)cc3.x * H + h];
    float w0 = __int_as_float(cc0.y), w1 = __int_as_float(cc1.y);
    float w2 = __int_as_float(cc2.y), w3 = __int_as_float(cc3.y);
    #pragma unroll
    for (int i = 0; i < CH; ++i) {
      acc[i] = fmaf(w0, (float)v0[i], acc[i]);
      acc[i] = fmaf(w1, (float)v1[i], acc[i]);
      acc[i] = fmaf(w2, (float)v2[i], acc[i]);
      acc[i] = fmaf(w3, (float)v3[i], acc[i]);
    }
  }
  for (; j < e; ++j) {
    int2 c = ew[j];
    float w = __int_as_float(c.y);
    HT v = Vv[(size_t)c.x * H + h];
    #pragma unroll
    for (int i = 0; i < CH; ++i) acc[i] = fmaf(w, (float)v[i], acc[i]);
  }
  HT u = ((const HT*)Up)[t];
  HT y;
  #pragma unroll
  for (int i = 0; i < CH; ++i) y[i] = (_Float16)fmaf(2.f, acc[i], (float)u[i]);
  ((HT*)Yp)[t] = y;
}

// out = A + L(Y) (+relu). OUT32: fp32 float4-chunks (final layer) else fp16.
template<int F, int CH, bool RELU, bool OUT32>
__global__ void __launch_bounds__(256) lapB_kernel(const void* __restrict__ Yp,
    const void* __restrict__ Ap,
    const int* __restrict__ start, const int* __restrict__ cnt,
    const int2* __restrict__ ew, void* __restrict__ outp, int N) {
  using HT = typename hvec_sel<CH>::T;
  constexpr int H = F / CH;
  const HT* __restrict__ Yv = (const HT*)Yp;
  int t = blockIdx.x * 256 + threadIdx.x;
  int n = t / H;
  if (n >= N) return;
  int h = t - n * H;
  int j = start[n], e = j + cnt[n];
  float acc[CH];
  #pragma unroll
  for (int i = 0; i < CH; ++i) acc[i] = 0.f;
  for (; j + 3 < e; j += 4) {
    int2 cc0 = ew[j], cc1 = ew[j + 1], cc2 = ew[j + 2], cc3 = ew[j + 3];
    HT v0 = Yv[(size_t)cc0.x * H + h];
    HT v1 = Yv[(size_t)cc1.x * H + h];
    HT v2 = Yv[(size_t)cc2.x * H + h];
    HT v3 = Yv[(size_t)cc3.x * H + h];
    float w0 = __int_as_float(cc0.y), w1 = __int_as_float(cc1.y);
    float w2 = __int_as_float(cc2.y), w3 = __int_as_float(cc3.y);
    #pragma unroll
    for (int i = 0; i < CH; ++i) {
      acc[i] = fmaf(w0, (float)v0[i], acc[i]);
      acc[i] = fmaf(w1, (float)v1[i], acc[i]);
      acc[i] = fmaf(w2, (float)v2[i], acc[i]);
      acc[i] = fmaf(w3, (float)v3[i], acc[i]);
    }
  }
  for (; j < e; ++j) {
    int2 c = ew[j];
    float w = __int_as_float(c.y);
    HT v = Yv[(size_t)c.x * H + h];
    #pragma unroll
    for (int i = 0; i < CH; ++i) acc[i] = fmaf(w, (float)v[i], acc[i]);
  }
  HT a = ((const HT*)Ap)[t];
  float r[CH];
  #pragma unroll
  for (int i = 0; i < CH; ++i) {
    r[i] = (float)a[i] + acc[i];
    if (RELU) r[i] = fmaxf(r[i], 0.f);
  }
  if constexpr (OUT32) {
    float4* o4 = (float4*)outp;
    #pragma unroll
    for (int q = 0; q < CH / 4; ++q)
      o4[(size_t)t * (CH / 4) + q] = make_float4(r[4 * q], r[4 * q + 1], r[4 * q + 2], r[4 * q + 3]);
  } else {
    HT y;
    #pragma unroll
    for (int i = 0; i < CH; ++i) y[i] = (_Float16)r[i];
    ((HT*)outp)[t] = y;
  }
}

// ---------------- launch ----------------

extern "C" void kernel_launch(void* const* d_in, const int* in_sizes, int n_in,
                              void* d_out, int out_size, void* d_ws, size_t ws_size,
                              hipStream_t stream) {
  const float* x  = (const float*)d_in[0];
  const int*   ei = (const int*)d_in[1];
  const float* W1 = (const float*)d_in[2];
  const float* b1 = (const float*)d_in[3];
  const float* Wm = (const float*)d_in[4];
  const float* bm = (const float*)d_in[5];
  const float* W2 = (const float*)d_in[6];
  const float* b2 = (const float*)d_in[7];
  float* out = (float*)d_out;
  const int N = NNODES;
  const int E = in_sizes[1] / 2;
  const int ES = (E + NS - 1) / NS;
  const int NB = (N + 255) / 256;  // 196

  char* p = (char*)d_ws;
  auto alloc = [&](size_t bytes) -> char* {
    char* q = p;
    p += (bytes + 255) & ~(size_t)255;
    return q;
  };
  int*      part_src = (int*)alloc((size_t)NS * NR * RSZ * 4);
  int*      part_dst = (int*)alloc((size_t)NS * NR * RSZ * 4);
  int*      cnt_dst  = (int*)alloc((size_t)N * 4);
  int*      startv   = (int*)alloc((size_t)N * 4);
  int*      bsum     = (int*)alloc(1024);
  float*    dis      = (float*)alloc((size_t)N * 4);
  int2*     ew       = (int2*)alloc((size_t)E * 8);
  _Float16* Xh       = (_Float16*)alloc((size_t)N * 64 * 2);
  _Float16* Ah       = (_Float16*)alloc((size_t)N * 64 * 2);
  _Float16* Uh       = (_Float16*)alloc((size_t)N * 64 * 2);
  _Float16* Vh       = (_Float16*)alloc((size_t)N * 64 * 2);
  _Float16* Yh       = (_Float16*)alloc((size_t)N * 64 * 2);
  _Float16* Bp1      = (_Float16*)alloc((size_t)128 * 192 * 2);
  _Float16* Bp2      = (_Float16*)alloc((size_t)64 * 192 * 2);
  _Float16* Bp3      = (_Float16*)alloc((size_t)64 * 48 * 2);

  // CSR build
  hist_kernel<<<dim3(NS, NR, 2), 256, 0, stream>>>(ei, E, ES, part_src, part_dst);
  reduce_kernel<<<NB, 256, 0, stream>>>(part_src, part_dst, dis, cnt_dst, N);
  scan1_kernel<<<NB, 256, 0, stream>>>(cnt_dst, startv, bsum, N);
  scan2_kernel<<<1, 256, 0, stream>>>(bsum, NB);
  scan3_kernel<<<NB, 256, 0, stream>>>(startv, bsum, N);
  fill_kernel<<<dim3(NS, NR), 256, 0, stream>>>(ei, E, ES, startv, part_dst, dis, ew);

  // Weight packs
  pack_kernel<128, 64><<<24, 256, 0, stream>>>(W1, Bp1);
  pack_kernel<64, 64><<<12, 256, 0, stream>>>(Wm, Bp2);
  pack_kernel<64, 16><<<3, 256, 0, stream>>>(W2, Bp3);

  const int gmm  = (N + 63) / 64;           // 782
  const int g64c = (N * 8 + 255) / 256;     // 1563  (F=64, CH=8)
  const int g16c = (N * 4 + 255) / 256;     // 782   (F=16, CH=4)

  // Layer 1: 128 -> 64, relu
  gemm_mfma_kernel<128, 64, float><<<gmm, 256, 0, stream>>>(x, Bp1, b1, Ah, Uh, Vh, N);
  lapA_kernel<64, 8><<<g64c, 256, 0, stream>>>(Vh, Uh, Yh, startv, cnt_dst, ew, N);
  lapB_kernel<64, 8, true, false><<<g64c, 256, 0, stream>>>(Yh, Ah, startv, cnt_dst, ew, Xh, N);

  // Layer 2: 64 -> 64, relu
  gemm_mfma_kernel<64, 64, _Float16><<<gmm, 256, 0, stream>>>(Xh, Bp2, bm, Ah, Uh, Vh, N);
  lapA_kernel<64, 8><<<g64c, 256, 0, stream>>>(Vh, Uh, Yh, startv, cnt_dst, ew, N);
  lapB_kernel<64, 8, true, false><<<g64c, 256, 0, stream>>>(Yh, Ah, startv, cnt_dst, ew, Xh, N);

  // Layer 3: 64 -> 16, no relu, fp32 out
  gemm_mfma_kernel<64, 16, _Float16><<<gmm, 256, 0, stream>>>(Xh, Bp3, b2, Ah, Uh, Vh, N);
  lapA_kernel<16, 4><<<g16c, 256, 0, stream>>>(Vh, Uh, Yh, startv, cnt_dst, ew, N);
  lapB_kernel<16, 4, false, true><<<g16c, 256, 0, stream>>>(Yh, Ah, startv, cnt_dst, ew, out, N);
}

// Round 6
// 269.390 us; speedup vs baseline: 1.9360x; 1.0706x over previous
//
#include <hip/hip_runtime.h>
#include <hip/hip_fp16.h>

constexpr int NNODES = 50000;
constexpr int NS  = 64;     // edge slices
constexpr int NR  = 4;      // node ranges
constexpr int RSZ = 12500;  // nodes per range (NR*RSZ >= NNODES)

typedef _Float16 half8_t __attribute__((ext_vector_type(8)));
typedef _Float16 half4_t __attribute__((ext_vector_type(4)));
typedef float    f32x4_t __attribute__((ext_vector_type(4)));

template<int CH> struct hvec_sel;
template<> struct hvec_sel<4> { using T = half4_t; };
template<> struct hvec_sel<8> { using T = half8_t; };

// ---------------- device helpers ----------------

// Weight pack into MFMA B-fragment order: lane holds B[k=(lane>>4)*8+j][n=lane&15].
template<int FIN, int FOUT>
__device__ void pack_dev(const float* __restrict__ W, _Float16* __restrict__ Bp,
                         int b, int nb) {
  constexpr int NT = 3 * FOUT / 16;
  constexpr int KT = FIN / 32;
  const int total = KT * NT * 512;
  for (int i = b * 256 + (int)threadIdx.x; i < total; i += nb * 256) {
    int j = i & 7;
    int lane = (i >> 3) & 63;
    int tile = i >> 9;
    int nt = tile % NT, kt = tile / NT;
    int k = kt * 32 + (lane >> 4) * 8 + j;
    int n = nt * 16 + (lane & 15);
    int cheb = n / FOUT, c = n - cheb * FOUT;
    Bp[i] = (_Float16)W[((size_t)cheb * FIN + k) * FOUT + c];
  }
}

// MFMA fused 3-way GEMM body. D = X @ [W0|W1|W2]; A = D0-D2+b ; U = D1 ; V = D2 (fp16).
template<int FIN, int FOUT, typename IN_T>
__device__ void gemm_dev(const IN_T* __restrict__ X, const _Float16* __restrict__ Bp,
                         const float* __restrict__ b, _Float16* __restrict__ A,
                         _Float16* __restrict__ U, _Float16* __restrict__ V,
                         int N, int blk, _Float16* xs) {
  constexpr int NT = 3 * FOUT / 16;
  constexpr int C3 = NT / 3;
  constexpr int KT = FIN / 32;
  constexpr int LDR = FIN + 8;   // 16B pad -> 2-way LDS alias (free)

  const int tid = threadIdx.x;
  const int row0 = blk * 64;

  for (int i = tid * 4; i < 64 * FIN; i += 1024) {
    int r = i / FIN, k = i - r * FIN;
    int row = row0 + r;
    short4 hv = make_short4(0, 0, 0, 0);
    if (row < N) {
      if constexpr (sizeof(IN_T) == 4) {
        float4 v = *(const float4*)((const float*)X + (size_t)row * FIN + k);
        _Float16 h0 = (_Float16)v.x, h1 = (_Float16)v.y, h2 = (_Float16)v.z, h3 = (_Float16)v.w;
        hv = make_short4(*(short*)&h0, *(short*)&h1, *(short*)&h2, *(short*)&h3);
      } else {
        hv = *(const short4*)((const _Float16*)X + (size_t)row * FIN + k);
      }
    }
    *(short4*)(&xs[r * LDR + k]) = hv;
  }
  __syncthreads();

  const int wave = tid >> 6, lane = tid & 63;
  const int m = lane & 15, quad = lane >> 4;

  f32x4_t acc[NT];
  #pragma unroll
  for (int nt = 0; nt < NT; ++nt) acc[nt] = (f32x4_t){0.f, 0.f, 0.f, 0.f};

  #pragma unroll
  for (int kt = 0; kt < KT; ++kt) {
    half8_t a = *(const half8_t*)(&xs[(wave * 16 + m) * LDR + kt * 32 + quad * 8]);
    const half8_t* bp = (const half8_t*)Bp + (size_t)(kt * NT) * 64 + lane;
    #pragma unroll
    for (int nt = 0; nt < NT; ++nt) {
      half8_t bf = bp[(size_t)nt * 64];
      acc[nt] = __builtin_amdgcn_mfma_f32_16x16x32_f16(a, bf, acc[nt], 0, 0, 0);
    }
  }

  const int row_b = row0 + wave * 16 + quad * 4;
  #pragma unroll
  for (int nt = 0; nt < C3; ++nt) {
    int c = nt * 16 + m;
    float bb = b[c];
    #pragma unroll
    for (int r = 0; r < 4; ++r) {
      int row = row_b + r;
      if (row < N) {
        size_t o = (size_t)row * FOUT + c;
        A[o] = (_Float16)(acc[nt][r] - acc[nt + 2 * C3][r] + bb);
        U[o] = (_Float16)acc[nt + C3][r];
        V[o] = (_Float16)acc[nt + 2 * C3][r];
      }
    }
  }
}

// ---------------- K1: hist (512 blocks) + weight packs (39 blocks) ----------------

__global__ void __launch_bounds__(256) k1_hist_pack(const int* __restrict__ ei, int E, int ES,
    int* __restrict__ part_src, int* __restrict__ part_dst,
    const float* __restrict__ W1, const float* __restrict__ Wm, const float* __restrict__ W2,
    _Float16* __restrict__ Bp1, _Float16* __restrict__ Bp2, _Float16* __restrict__ Bp3) {
  __shared__ int sh[RSZ];
  const int bid = blockIdx.x;
  if (bid < 512) {
    // hist role: z = bid&1, r = (bid>>1)&3, s = bid>>3
    const int z = bid & 1, r = (bid >> 1) & 3, s = bid >> 3;
    for (int i = threadIdx.x; i < RSZ; i += 256) sh[i] = 0;
    __syncthreads();
    const int lo = r * RSZ;
    const int* __restrict__ idxarr = ei + (z ? E : 0);
    const int e0 = s * ES, e1 = min(e0 + ES, E);
    for (int e = e0 + (int)threadIdx.x; e < e1; e += 256) {
      unsigned u = (unsigned)(idxarr[e] - lo);
      if (u < (unsigned)RSZ) atomicAdd(&sh[u], 1);
    }
    __syncthreads();
    int* __restrict__ part = z ? part_dst : part_src;
    const int base = (s * NR + r) * RSZ;
    for (int i = threadIdx.x; i < RSZ; i += 256) part[base + i] = sh[i];
  } else if (bid < 536) {
    pack_dev<128, 64>(W1, Bp1, bid - 512, 24);
  } else if (bid < 548) {
    pack_dev<64, 64>(Wm, Bp2, bid - 536, 12);
  } else {
    pack_dev<64, 16>(W2, Bp3, bid - 548, 3);
  }
}

// ---------------- K2: reduce + in-block scan (196 blocks) ----------------
// Per node: src-degree -> dis; dst partials -> per-slice exclusive prefix (in place);
// node total -> cnt; block-exclusive scan of totals -> exc + bsum[block].

__global__ void __launch_bounds__(256) k2_reduce_scan(const int* __restrict__ part_src,
    int* __restrict__ part_dst, float* __restrict__ dis, int* __restrict__ cnt,
    int* __restrict__ exc, int* __restrict__ bsum, int N) {
  __shared__ int sh[256];
  const int tid = threadIdx.x;
  const int n = blockIdx.x * 256 + tid;
  int off = 0;
  if (n < N) {
    int r = n / RSZ, i = n - r * RSZ;
    int ssum = 0;
    #pragma unroll 4
    for (int s = 0; s < NS; ++s) ssum += part_src[(size_t)(s * NR + r) * RSZ + i];
    dis[n] = (ssum > 0) ? rsqrtf((float)ssum) : 0.0f;
    for (int s = 0; s < NS; ++s) {
      size_t idx = (size_t)(s * NR + r) * RSZ + i;
      int c = part_dst[idx];
      part_dst[idx] = off;
      off += c;
    }
    cnt[n] = off;
  }
  int acc = off;
  sh[tid] = acc; __syncthreads();
  #pragma unroll
  for (int o = 1; o < 256; o <<= 1) {
    int t = (tid >= o) ? sh[tid - o] : 0;
    __syncthreads();
    acc += t;
    sh[tid] = acc;
    __syncthreads();
  }
  if (n < N) exc[n] = acc - off;
  if (tid == 255) bsum[blockIdx.x] = acc;
}

// ---------------- K2b: scan block sums (1 block) ----------------

__global__ void __launch_bounds__(256) k2b_scan2(int* __restrict__ bsum, int NB) {
  __shared__ int sh[256];
  int tid = threadIdx.x;
  int v = (tid < NB) ? bsum[tid] : 0;
  int acc = v;
  sh[tid] = acc; __syncthreads();
  #pragma unroll
  for (int o = 1; o < 256; o <<= 1) {
    int t = (tid >= o) ? sh[tid - o] : 0;
    __syncthreads();
    acc += t;
    sh[tid] = acc;
    __syncthreads();
  }
  if (tid < NB) bsum[tid] = acc - v;
}

// ---------------- K3: fill (256 blocks) + gemm1 (782 blocks) ----------------
// fill: pos = (exc[d]+bsumx[d>>8]) + sliceoff[s][d] + LDS-cursor rank. No global atomics.

__global__ void __launch_bounds__(256) k3_fill_gemm1(const int* __restrict__ ei, int E, int ES,
    const int* __restrict__ exc, const int* __restrict__ bsumx,
    const int* __restrict__ pd_off, const float* __restrict__ dis, int2* __restrict__ ew,
    const float* __restrict__ x, const _Float16* __restrict__ Bp1, const float* __restrict__ b1,
    _Float16* __restrict__ Ah, _Float16* __restrict__ Uh, _Float16* __restrict__ Vh, int N) {
  __shared__ __align__(16) char smem[50048];
  const int bid = blockIdx.x;
  if (bid < 256) {
    int* cur = (int*)smem;
    for (int i = threadIdx.x; i < RSZ; i += 256) cur[i] = 0;
    __syncthreads();
    const int s = bid >> 2, r = bid & 3;
    const int lo = r * RSZ;
    const int base = (s * NR + r) * RSZ;
    const int e0 = s * ES, e1 = min(e0 + ES, E);
    for (int e = e0 + (int)threadIdx.x; e < e1; e += 256) {
      int sv = ei[e], d = ei[E + e];
      unsigned u = (unsigned)(d - lo);
      if (u < (unsigned)RSZ) {
        int rank = atomicAdd(&cur[u], 1);
        int pos = exc[d] + bsumx[d >> 8] + pd_off[base + u] + rank;
        float w = -dis[sv] * dis[d];   // pre-negated: lap = sum(w * v[src])
        ew[pos] = make_int2(sv, __float_as_int(w));
      }
    }
  } else {
    gemm_dev<128, 64, float>(x, Bp1, b1, Ah, Uh, Vh, N, bid - 256, (_Float16*)smem);
  }
}

// ---------------- standalone MFMA GEMM (layers 2,3) ----------------

template<int FIN, int FOUT>
__global__ void __launch_bounds__(256) gemm_mfma_kernel(const _Float16* __restrict__ X,
    const _Float16* __restrict__ Bp, const float* __restrict__ b,
    _Float16* __restrict__ A, _Float16* __restrict__ U, _Float16* __restrict__ V, int N) {
  __shared__ _Float16 xs[64 * (FIN + 8)];
  gemm_dev<FIN, FOUT, _Float16>(X, Bp, b, A, U, V, N, blockIdx.x, xs);
}

// ---------------- Laplacian propagation (CSR gather, wide fp16 chunks, unroll 8) ----------------
// Thread owns (node n, CH-feature chunk h). start[n] = exc[n] + bsumx[n>>8].

// Y = half(U + 2 * L(V))
template<int F, int CH>
__global__ void __launch_bounds__(256) lapA_kernel(const void* __restrict__ Vp,
    const void* __restrict__ Up, void* __restrict__ Yp,
    const int* __restrict__ exc, const int* __restrict__ cnt, const int* __restrict__ bsumx,
    const int2* __restrict__ ew, int N) {
  using HT = typename hvec_sel<CH>::T;
  constexpr int H = F / CH;
  const HT* __restrict__ Vv = (const HT*)Vp;
  int t = blockIdx.x * 256 + threadIdx.x;
  int n = t / H;
  if (n >= N) return;
  int h = t - n * H;
  int j = exc[n] + bsumx[n >> 8];
  int e = j + cnt[n];
  float acc[CH];
  #pragma unroll
  for (int i = 0; i < CH; ++i) acc[i] = 0.f;
  for (; j + 7 < e; j += 8) {
    int2 c[8]; HT v[8];
    #pragma unroll
    for (int q = 0; q < 8; ++q) c[q] = ew[j + q];
    #pragma unroll
    for (int q = 0; q < 8; ++q) v[q] = Vv[(size_t)c[q].x * H + h];
    #pragma unroll
    for (int q = 0; q < 8; ++q) {
      float w = __int_as_float(c[q].y);
      #pragma unroll
      for (int i = 0; i < CH; ++i) acc[i] = fmaf(w, (float)v[q][i], acc[i]);
    }
  }
  for (; j + 3 < e; j += 4) {
    int2 c[4]; HT v[4];
    #pragma unroll
    for (int q = 0; q < 4; ++q) c[q] = ew[j + q];
    #pragma unroll
    for (int q = 0; q < 4; ++q) v[q] = Vv[(size_t)c[q].x * H + h];
    #pragma unroll
    for (int q = 0; q < 4; ++q) {
      float w = __int_as_float(c[q].y);
      #pragma unroll
      for (int i = 0; i < CH; ++i) acc[i] = fmaf(w, (float)v[q][i], acc[i]);
    }
  }
  for (; j < e; ++j) {
    int2 c = ew[j];
    float w = __int_as_float(c.y);
    HT v = Vv[(size_t)c.x * H + h];
    #pragma unroll
    for (int i = 0; i < CH; ++i) acc[i] = fmaf(w, (float)v[i], acc[i]);
  }
  HT u = ((const HT*)Up)[t];
  HT y;
  #pragma unroll
  for (int i = 0; i < CH; ++i) y[i] = (_Float16)fmaf(2.f, acc[i], (float)u[i]);
  ((HT*)Yp)[t] = y;
}

// out = A + L(Y) (+relu). OUT32: fp32 float4-chunks (final layer) else fp16.
template<int F, int CH, bool RELU, bool OUT32>
__global__ void __launch_bounds__(256) lapB_kernel(const void* __restrict__ Yp,
    const void* __restrict__ Ap,
    const int* __restrict__ exc, const int* __restrict__ cnt, const int* __restrict__ bsumx,
    const int2* __restrict__ ew, void* __restrict__ outp, int N) {
  using HT = typename hvec_sel<CH>::T;
  constexpr int H = F / CH;
  const HT* __restrict__ Yv = (const HT*)Yp;
  int t = blockIdx.x * 256 + threadIdx.x;
  int n = t / H;
  if (n >= N) return;
  int h = t - n * H;
  int j = exc[n] + bsumx[n >> 8];
  int e = j + cnt[n];
  float acc[CH];
  #pragma unroll
  for (int i = 0; i < CH; ++i) acc[i] = 0.f;
  for (; j + 7 < e; j += 8) {
    int2 c[8]; HT v[8];
    #pragma unroll
    for (int q = 0; q < 8; ++q) c[q] = ew[j + q];
    #pragma unroll
    for (int q = 0; q < 8; ++q) v[q] = Yv[(size_t)c[q].x * H + h];
    #pragma unroll
    for (int q = 0; q < 8; ++q) {
      float w = __int_as_float(c[q].y);
      #pragma unroll
      for (int i = 0; i < CH; ++i) acc[i] = fmaf(w, (float)v[q][i], acc[i]);
    }
  }
  for (; j + 3 < e; j += 4) {
    int2 c[4]; HT v[4];
    #pragma unroll
    for (int q = 0; q < 4; ++q) c[q] = ew[j + q];
    #pragma unroll
    for (int q = 0; q < 4; ++q) v[q] = Yv[(size_t)c[q].x * H + h];
    #pragma unroll
    for (int q = 0; q < 4; ++q) {
      float w = __int_as_float(c[q].y);
      #pragma unroll
      for (int i = 0; i < CH; ++i) acc[i] = fmaf(w, (float)v[q][i], acc[i]);
    }
  }
  for (; j < e; ++j) {
    int2 c = ew[j];
    float w = __int_as_float(c.y);
    HT v = Yv[(size_t)c.x * H + h];
    #pragma unroll
    for (int i = 0; i < CH; ++i) acc[i] = fmaf(w, (float)v[i], acc[i]);
  }
  HT a = ((const HT*)Ap)[t];
  float r[CH];
  #pragma unroll
  for (int i = 0; i < CH; ++i) {
    r[i] = (float)a[i] + acc[i];
    if (RELU) r[i] = fmaxf(r[i], 0.f);
  }
  if constexpr (OUT32) {
    float4* o4 = (float4*)outp;
    #pragma unroll
    for (int q = 0; q < CH / 4; ++q)
      o4[(size_t)t * (CH / 4) + q] = make_float4(r[4 * q], r[4 * q + 1], r[4 * q + 2], r[4 * q + 3]);
  } else {
    HT y;
    #pragma unroll
    for (int i = 0; i < CH; ++i) y[i] = (_Float16)r[i];
    ((HT*)outp)[t] = y;
  }
}

// ---------------- launch ----------------

extern "C" void kernel_launch(void* const* d_in, const int* in_sizes, int n_in,
                              void* d_out, int out_size, void* d_ws, size_t ws_size,
                              hipStream_t stream) {
  const float* x  = (const float*)d_in[0];
  const int*   ei = (const int*)d_in[1];
  const float* W1 = (const float*)d_in[2];
  const float* b1 = (const float*)d_in[3];
  const float* Wm = (const float*)d_in[4];
  const float* bm = (const float*)d_in[5];
  const float* W2 = (const float*)d_in[6];
  const float* b2 = (const float*)d_in[7];
  float* out = (float*)d_out;
  const int N = NNODES;
  const int E = in_sizes[1] / 2;
  const int ES = (E + NS - 1) / NS;
  const int NB = (N + 255) / 256;  // 196

  char* p = (char*)d_ws;
  auto alloc = [&](size_t bytes) -> char* {
    char* q = p;
    p += (bytes + 255) & ~(size_t)255;
    return q;
  };
  int*      part_src = (int*)alloc((size_t)NS * NR * RSZ * 4);
  int*      part_dst = (int*)alloc((size_t)NS * NR * RSZ * 4);
  int*      cnt      = (int*)alloc((size_t)N * 4);
  int*      exc      = (int*)alloc((size_t)N * 4);
  int*      bsum     = (int*)alloc(1024);
  float*    dis      = (float*)alloc((size_t)N * 4);
  int2*     ew       = (int2*)alloc((size_t)E * 8);
  _Float16* Xh       = (_Float16*)alloc((size_t)N * 64 * 2);
  _Float16* Ah       = (_Float16*)alloc((size_t)N * 64 * 2);
  _Float16* Uh       = (_Float16*)alloc((size_t)N * 64 * 2);
  _Float16* Vh       = (_Float16*)alloc((size_t)N * 64 * 2);
  _Float16* Yh       = (_Float16*)alloc((size_t)N * 64 * 2);
  _Float16* Bp1      = (_Float16*)alloc((size_t)128 * 192 * 2);
  _Float16* Bp2      = (_Float16*)alloc((size_t)64 * 192 * 2);
  _Float16* Bp3      = (_Float16*)alloc((size_t)64 * 48 * 2);

  // K1: histograms + weight packs (independent work, one launch)
  k1_hist_pack<<<551, 256, 0, stream>>>(ei, E, ES, part_src, part_dst,
                                        W1, Wm, W2, Bp1, Bp2, Bp3);
  // K2: per-node reduce + per-slice prefix + block-local scan
  k2_reduce_scan<<<NB, 256, 0, stream>>>(part_src, part_dst, dis, cnt, exc, bsum, N);
  // K2b: scan block sums
  k2b_scan2<<<1, 256, 0, stream>>>(bsum, NB);
  // K3: CSR fill + layer-1 GEMM (independent, one launch)
  k3_fill_gemm1<<<256 + 782, 256, 0, stream>>>(ei, E, ES, exc, bsum, part_dst, dis, ew,
                                               x, Bp1, b1, Ah, Uh, Vh, N);

  const int gmm  = (N + 63) / 64;           // 782
  const int g64c = (N * 8 + 255) / 256;     // 1563  (F=64, CH=8)
  const int g16c = (N * 4 + 255) / 256;     // 782   (F=16, CH=4)

  // Layer 1 laps (relu)
  lapA_kernel<64, 8><<<g64c, 256, 0, stream>>>(Vh, Uh, Yh, exc, cnt, bsum, ew, N);
  lapB_kernel<64, 8, true, false><<<g64c, 256, 0, stream>>>(Yh, Ah, exc, cnt, bsum, ew, Xh, N);

  // Layer 2: 64 -> 64, relu
  gemm_mfma_kernel<64, 64><<<gmm, 256, 0, stream>>>(Xh, Bp2, bm, Ah, Uh, Vh, N);
  lapA_kernel<64, 8><<<g64c, 256, 0, stream>>>(Vh, Uh, Yh, exc, cnt, bsum, ew, N);
  lapB_kernel<64, 8, true, false><<<g64c, 256, 0, stream>>>(Yh, Ah, exc, cnt, bsum, ew, Xh, N);

  // Layer 3: 64 -> 16, no relu, fp32 out
  gemm_mfma_kernel<64, 16><<<gmm, 256, 0, stream>>>(Xh, Bp3, b2, Ah, Uh, Vh, N);
  lapA_kernel<16, 4><<<g16c, 256, 0, stream>>>(Vh, Uh, Yh, exc, cnt, bsum, ew, N);
  lapB_kernel<16, 4, false, true><<<g16c, 256, 0, stream>>>(Yh, Ah, exc, cnt, bsum, ew, out, N);
}

// Round 7
// 250.444 us; speedup vs baseline: 2.0825x; 1.0757x over previous
//
#include <hip/hip_runtime.h>
#include <hip/hip_fp16.h>

constexpr int NNODES = 50000;
constexpr int NS  = 64;     // edge slices
constexpr int NR  = 4;      // node ranges
constexpr int RSZ = 12500;  // nodes per range (NR*RSZ >= NNODES)

typedef _Float16 half8_t __attribute__((ext_vector_type(8)));
typedef _Float16 half4_t __attribute__((ext_vector_type(4)));
typedef float    f32x4_t __attribute__((ext_vector_type(4)));

template<int CH> struct hvec_sel;
template<> struct hvec_sel<4> { using T = half4_t; };
template<> struct hvec_sel<8> { using T = half8_t; };

__device__ __forceinline__ float w_of(unsigned ec) {
  unsigned short wb = (unsigned short)(ec >> 16);
  return (float)__builtin_bit_cast(_Float16, wb);
}

// ---------------- device helpers ----------------

// Weight pack into MFMA B-fragment order: lane holds B[k=(lane>>4)*8+j][n=lane&15].
template<int FIN, int FOUT>
__device__ void pack_dev(const float* __restrict__ W, _Float16* __restrict__ Bp,
                         int b, int nb) {
  constexpr int NT = 3 * FOUT / 16;
  constexpr int KT = FIN / 32;
  const int total = KT * NT * 512;
  for (int i = b * 256 + (int)threadIdx.x; i < total; i += nb * 256) {
    int j = i & 7;
    int lane = (i >> 3) & 63;
    int tile = i >> 9;
    int nt = tile % NT, kt = tile / NT;
    int k = kt * 32 + (lane >> 4) * 8 + j;
    int n = nt * 16 + (lane & 15);
    int cheb = n / FOUT, c = n - cheb * FOUT;
    Bp[i] = (_Float16)W[((size_t)cheb * FIN + k) * FOUT + c];
  }
}

// MFMA fused 3-way GEMM body. D = X @ [W0|W1|W2]; A = D0-D2+b ; U = D1 ; V = D2 (fp16).
template<int FIN, int FOUT, typename IN_T>
__device__ void gemm_dev(const IN_T* __restrict__ X, const _Float16* __restrict__ Bp,
                         const float* __restrict__ b, _Float16* __restrict__ A,
                         _Float16* __restrict__ U, _Float16* __restrict__ V,
                         int N, int blk, _Float16* xs) {
  constexpr int NT = 3 * FOUT / 16;
  constexpr int C3 = NT / 3;
  constexpr int KT = FIN / 32;
  constexpr int LDR = FIN + 8;   // 16B pad -> 2-way LDS alias (free)

  const int tid = threadIdx.x;
  const int row0 = blk * 64;

  for (int i = tid * 4; i < 64 * FIN; i += 1024) {
    int r = i / FIN, k = i - r * FIN;
    int row = row0 + r;
    short4 hv = make_short4(0, 0, 0, 0);
    if (row < N) {
      if constexpr (sizeof(IN_T) == 4) {
        float4 v = *(const float4*)((const float*)X + (size_t)row * FIN + k);
        _Float16 h0 = (_Float16)v.x, h1 = (_Float16)v.y, h2 = (_Float16)v.z, h3 = (_Float16)v.w;
        hv = make_short4(*(short*)&h0, *(short*)&h1, *(short*)&h2, *(short*)&h3);
      } else {
        hv = *(const short4*)((const _Float16*)X + (size_t)row * FIN + k);
      }
    }
    *(short4*)(&xs[r * LDR + k]) = hv;
  }
  __syncthreads();

  const int wave = tid >> 6, lane = tid & 63;
  const int m = lane & 15, quad = lane >> 4;

  f32x4_t acc[NT];
  #pragma unroll
  for (int nt = 0; nt < NT; ++nt) acc[nt] = (f32x4_t){0.f, 0.f, 0.f, 0.f};

  #pragma unroll
  for (int kt = 0; kt < KT; ++kt) {
    half8_t a = *(const half8_t*)(&xs[(wave * 16 + m) * LDR + kt * 32 + quad * 8]);
    const half8_t* bp = (const half8_t*)Bp + (size_t)(kt * NT) * 64 + lane;
    #pragma unroll
    for (int nt = 0; nt < NT; ++nt) {
      half8_t bf = bp[(size_t)nt * 64];
      acc[nt] = __builtin_amdgcn_mfma_f32_16x16x32_f16(a, bf, acc[nt], 0, 0, 0);
    }
  }

  const int row_b = row0 + wave * 16 + quad * 4;
  #pragma unroll
  for (int nt = 0; nt < C3; ++nt) {
    int c = nt * 16 + m;
    float bb = b[c];
    #pragma unroll
    for (int r = 0; r < 4; ++r) {
      int row = row_b + r;
      if (row < N) {
        size_t o = (size_t)row * FOUT + c;
        A[o] = (_Float16)(acc[nt][r] - acc[nt + 2 * C3][r] + bb);
        U[o] = (_Float16)acc[nt + C3][r];
        V[o] = (_Float16)acc[nt + 2 * C3][r];
      }
    }
  }
}

// ---------------- K1: hist + rank capture (512 blocks) + weight packs (39 blocks) ----------------
// part layout: part[s*N + n] (ushort). z=1 blocks also record rank[e] (uchar) =
// edge's arrival order within its (slice, node) bucket.

__global__ void __launch_bounds__(256) k1_hist_pack(const int* __restrict__ ei, int E, int ES,
    unsigned short* __restrict__ part_src, unsigned short* __restrict__ part_dst,
    unsigned char* __restrict__ rank,
    const float* __restrict__ W1, const float* __restrict__ Wm, const float* __restrict__ W2,
    _Float16* __restrict__ Bp1, _Float16* __restrict__ Bp2, _Float16* __restrict__ Bp3,
    int N) {
  __shared__ int sh[RSZ];
  const int bid = blockIdx.x;
  if (bid < 512) {
    const int z = bid & 1, r = (bid >> 1) & 3, s = bid >> 3;
    for (int i = threadIdx.x; i < RSZ; i += 256) sh[i] = 0;
    __syncthreads();
    const int lo = r * RSZ;
    const int* __restrict__ idxarr = ei + (z ? E : 0);
    const int e0 = s * ES, e1 = min(e0 + ES, E);
    if (z) {
      for (int e = e0 + (int)threadIdx.x; e < e1; e += 256) {
        unsigned u = (unsigned)(idxarr[e] - lo);
        if (u < (unsigned)RSZ) {
          int rk = atomicAdd(&sh[u], 1);
          rank[e] = (unsigned char)rk;
        }
      }
    } else {
      for (int e = e0 + (int)threadIdx.x; e < e1; e += 256) {
        unsigned u = (unsigned)(idxarr[e] - lo);
        if (u < (unsigned)RSZ) atomicAdd(&sh[u], 1);
      }
    }
    __syncthreads();
    unsigned short* __restrict__ part = z ? part_dst : part_src;
    const size_t base = (size_t)s * N + lo;
    for (int i = threadIdx.x; i < RSZ && lo + i < N; i += 256)
      part[base + i] = (unsigned short)sh[i];
  } else if (bid < 536) {
    pack_dev<128, 64>(W1, Bp1, bid - 512, 24);
  } else if (bid < 548) {
    pack_dev<64, 64>(Wm, Bp2, bid - 536, 12);
  } else {
    pack_dev<64, 16>(W2, Bp3, bid - 548, 3);
  }
}

// ---------------- K2: reduce + per-slice prefix + in-block scan (196 blocks) ----------------

__global__ void __launch_bounds__(256) k2_reduce_scan(const unsigned short* __restrict__ part_src,
    unsigned short* __restrict__ part_dst, _Float16* __restrict__ dis, int* __restrict__ cnt,
    int* __restrict__ exc, int* __restrict__ bsum, int N) {
  __shared__ int sh[256];
  const int tid = threadIdx.x;
  const int n = blockIdx.x * 256 + tid;
  int off = 0;
  if (n < N) {
    int ssum = 0;
    #pragma unroll 4
    for (int s = 0; s < NS; ++s) ssum += part_src[(size_t)s * N + n];
    dis[n] = (_Float16)((ssum > 0) ? rsqrtf((float)ssum) : 0.0f);
    for (int s = 0; s < NS; ++s) {
      size_t idx = (size_t)s * N + n;
      int c = part_dst[idx];
      part_dst[idx] = (unsigned short)off;
      off += c;
    }
    cnt[n] = off;
  }
  int acc = off;
  sh[tid] = acc; __syncthreads();
  #pragma unroll
  for (int o = 1; o < 256; o <<= 1) {
    int t = (tid >= o) ? sh[tid - o] : 0;
    __syncthreads();
    acc += t;
    sh[tid] = acc;
    __syncthreads();
  }
  if (n < N) exc[n] = acc - off;
  if (tid == 255) bsum[blockIdx.x] = acc;
}

// ---------------- K2b: scan block sums (1 block) ----------------

__global__ void __launch_bounds__(256) k2b_scan2(int* __restrict__ bsum, int NB) {
  __shared__ int sh[256];
  int tid = threadIdx.x;
  int v = (tid < NB) ? bsum[tid] : 0;
  int acc = v;
  sh[tid] = acc; __syncthreads();
  #pragma unroll
  for (int o = 1; o < 256; o <<= 1) {
    int t = (tid >= o) ? sh[tid - o] : 0;
    __syncthreads();
    acc += t;
    sh[tid] = acc;
    __syncthreads();
  }
  if (tid < NB) bsum[tid] = acc - v;
}

// ---------------- K3: fill (256 blocks, LDS-free grid-stride) + gemm1 (782 blocks) ----------
// pos = exc[d] + bsumx[d>>8] + pd_off[s][d] + rank[e].  ew = sv | half(dis[sv])<<16.

__global__ void __launch_bounds__(256) k3_fill_gemm1(const int* __restrict__ ei, int E, int ES,
    const int* __restrict__ exc, const int* __restrict__ bsumx,
    const unsigned short* __restrict__ pd_off, const unsigned char* __restrict__ rank,
    const unsigned short* __restrict__ dis_u, unsigned* __restrict__ ew,
    const float* __restrict__ x, const _Float16* __restrict__ Bp1, const float* __restrict__ b1,
    _Float16* __restrict__ Ah, _Float16* __restrict__ Uh, _Float16* __restrict__ Vh, int N) {
  __shared__ _Float16 xs[64 * (128 + 8)];
  const int bid = blockIdx.x;
  if (bid < 256) {
    for (int e = bid * 256 + (int)threadIdx.x; e < E; e += 256 * 256) {
      int sv = ei[e], d = ei[E + e];
      int s = e / ES;
      int pos = exc[d] + bsumx[d >> 8] + (int)pd_off[(size_t)s * N + d] + (int)rank[e];
      unsigned w16 = dis_u[sv];
      ew[pos] = (unsigned)sv | (w16 << 16);
    }
  } else {
    gemm_dev<128, 64, float>(x, Bp1, b1, Ah, Uh, Vh, N, bid - 256, xs);
  }
}

// ---------------- standalone MFMA GEMM (layers 2,3) ----------------

template<int FIN, int FOUT>
__global__ void __launch_bounds__(256) gemm_mfma_kernel(const _Float16* __restrict__ X,
    const _Float16* __restrict__ Bp, const float* __restrict__ b,
    _Float16* __restrict__ A, _Float16* __restrict__ U, _Float16* __restrict__ V, int N) {
  __shared__ _Float16 xs[64 * (FIN + 8)];
  gemm_dev<FIN, FOUT, _Float16>(X, Bp, b, A, U, V, N, blockIdx.x, xs);
}

// ---------------- Laplacian propagation ----------------
// lap_d = -dis[d] * sum_j dis[s_j] * v[s_j].  Thread owns (node n, CH-feature chunk h).
// start[n] = exc[n] + bsumx[n>>8].

// Y = half(U + 2 * L(V))
template<int F, int CH>
__global__ void __launch_bounds__(256) lapA_kernel(const void* __restrict__ Vp,
    const void* __restrict__ Up, void* __restrict__ Yp,
    const int* __restrict__ exc, const int* __restrict__ cnt, const int* __restrict__ bsumx,
    const unsigned* __restrict__ ew, const _Float16* __restrict__ dis, int N) {
  using HT = typename hvec_sel<CH>::T;
  constexpr int H = F / CH;
  const HT* __restrict__ Vv = (const HT*)Vp;
  int t = blockIdx.x * 256 + threadIdx.x;
  int n = t / H;
  if (n >= N) return;
  int h = t - n * H;
  int j = exc[n] + bsumx[n >> 8];
  int e = j + cnt[n];
  float acc[CH];
  #pragma unroll
  for (int i = 0; i < CH; ++i) acc[i] = 0.f;
  for (; j + 7 < e; j += 8) {
    unsigned c[8]; HT v[8];
    #pragma unroll
    for (int q = 0; q < 8; ++q) c[q] = ew[j + q];
    #pragma unroll
    for (int q = 0; q < 8; ++q) v[q] = Vv[(size_t)(c[q] & 0xFFFF) * H + h];
    #pragma unroll
    for (int q = 0; q < 8; ++q) {
      float w = w_of(c[q]);
      #pragma unroll
      for (int i = 0; i < CH; ++i) acc[i] = fmaf(w, (float)v[q][i], acc[i]);
    }
  }
  for (; j + 3 < e; j += 4) {
    unsigned c[4]; HT v[4];
    #pragma unroll
    for (int q = 0; q < 4; ++q) c[q] = ew[j + q];
    #pragma unroll
    for (int q = 0; q < 4; ++q) v[q] = Vv[(size_t)(c[q] & 0xFFFF) * H + h];
    #pragma unroll
    for (int q = 0; q < 4; ++q) {
      float w = w_of(c[q]);
      #pragma unroll
      for (int i = 0; i < CH; ++i) acc[i] = fmaf(w, (float)v[q][i], acc[i]);
    }
  }
  for (; j < e; ++j) {
    unsigned c = ew[j];
    float w = w_of(c);
    HT v = Vv[(size_t)(c & 0xFFFF) * H + h];
    #pragma unroll
    for (int i = 0; i < CH; ++i) acc[i] = fmaf(w, (float)v[i], acc[i]);
  }
  float s2 = -2.f * (float)dis[n];
  HT u = ((const HT*)Up)[t];
  HT y;
  #pragma unroll
  for (int i = 0; i < CH; ++i) y[i] = (_Float16)fmaf(s2, acc[i], (float)u[i]);
  ((HT*)Yp)[t] = y;
}

// out = A + L(Y) (+relu). OUT32: fp32 float4-chunks (final layer) else fp16.
template<int F, int CH, bool RELU, bool OUT32>
__global__ void __launch_bounds__(256) lapB_kernel(const void* __restrict__ Yp,
    const void* __restrict__ Ap,
    const int* __restrict__ exc, const int* __restrict__ cnt, const int* __restrict__ bsumx,
    const unsigned* __restrict__ ew, const _Float16* __restrict__ dis,
    void* __restrict__ outp, int N) {
  using HT = typename hvec_sel<CH>::T;
  constexpr int H = F / CH;
  const HT* __restrict__ Yv = (const HT*)Yp;
  int t = blockIdx.x * 256 + threadIdx.x;
  int n = t / H;
  if (n >= N) return;
  int h = t - n * H;
  int j = exc[n] + bsumx[n >> 8];
  int e = j + cnt[n];
  float acc[CH];
  #pragma unroll
  for (int i = 0; i < CH; ++i) acc[i] = 0.f;
  for (; j + 7 < e; j += 8) {
    unsigned c[8]; HT v[8];
    #pragma unroll
    for (int q = 0; q < 8; ++q) c[q] = ew[j + q];
    #pragma unroll
    for (int q = 0; q < 8; ++q) v[q] = Yv[(size_t)(c[q] & 0xFFFF) * H + h];
    #pragma unroll
    for (int q = 0; q < 8; ++q) {
      float w = w_of(c[q]);
      #pragma unroll
      for (int i = 0; i < CH; ++i) acc[i] = fmaf(w, (float)v[q][i], acc[i]);
    }
  }
  for (; j + 3 < e; j += 4) {
    unsigned c[4]; HT v[4];
    #pragma unroll
    for (int q = 0; q < 4; ++q) c[q] = ew[j + q];
    #pragma unroll
    for (int q = 0; q < 4; ++q) v[q] = Yv[(size_t)(c[q] & 0xFFFF) * H + h];
    #pragma unroll
    for (int q = 0; q < 4; ++q) {
      float w = w_of(c[q]);
      #pragma unroll
      for (int i = 0; i < CH; ++i) acc[i] = fmaf(w, (float)v[q][i], acc[i]);
    }
  }
  for (; j < e; ++j) {
    unsigned c = ew[j];
    float w = w_of(c);
    HT v = Yv[(size_t)(c & 0xFFFF) * H + h];
    #pragma unroll
    for (int i = 0; i < CH; ++i) acc[i] = fmaf(w, (float)v[i], acc[i]);
  }
  float s1 = -(float)dis[n];
  HT a = ((const HT*)Ap)[t];
  float r[CH];
  #pragma unroll
  for (int i = 0; i < CH; ++i) {
    r[i] = fmaf(s1, acc[i], (float)a[i]);
    if (RELU) r[i] = fmaxf(r[i], 0.f);
  }
  if constexpr (OUT32) {
    float4* o4 = (float4*)outp;
    #pragma unroll
    for (int q = 0; q < CH / 4; ++q)
      o4[(size_t)t * (CH / 4) + q] = make_float4(r[4 * q], r[4 * q + 1], r[4 * q + 2], r[4 * q + 3]);
  } else {
    HT y;
    #pragma unroll
    for (int i = 0; i < CH; ++i) y[i] = (_Float16)r[i];
    ((HT*)outp)[t] = y;
  }
}

// ---------------- launch ----------------

extern "C" void kernel_launch(void* const* d_in, const int* in_sizes, int n_in,
                              void* d_out, int out_size, void* d_ws, size_t ws_size,
                              hipStream_t stream) {
  const float* x  = (const float*)d_in[0];
  const int*   ei = (const int*)d_in[1];
  const float* W1 = (const float*)d_in[2];
  const float* b1 = (const float*)d_in[3];
  const float* Wm = (const float*)d_in[4];
  const float* bm = (const float*)d_in[5];
  const float* W2 = (const float*)d_in[6];
  const float* b2 = (const float*)d_in[7];
  float* out = (float*)d_out;
  const int N = NNODES;
  const int E = in_sizes[1] / 2;
  const int ES = (E + NS - 1) / NS;
  const int NB = (N + 255) / 256;  // 196

  char* p = (char*)d_ws;
  auto alloc = [&](size_t bytes) -> char* {
    char* q = p;
    p += (bytes + 255) & ~(size_t)255;
    return q;
  };
  unsigned short* part_src = (unsigned short*)alloc((size_t)NS * N * 2);   // 6.4 MB
  unsigned short* part_dst = (unsigned short*)alloc((size_t)NS * N * 2);   // 6.4 MB
  unsigned char*  rank     = (unsigned char*)alloc((size_t)E);             // 0.8 MB
  int*            cnt      = (int*)alloc((size_t)N * 4);
  int*            exc      = (int*)alloc((size_t)N * 4);
  int*            bsum     = (int*)alloc(1024);
  _Float16*       dis      = (_Float16*)alloc((size_t)N * 2);
  unsigned*       ew       = (unsigned*)alloc((size_t)E * 4);              // 3.2 MB
  _Float16* Xh  = (_Float16*)alloc((size_t)N * 64 * 2);
  _Float16* Ah  = (_Float16*)alloc((size_t)N * 64 * 2);
  _Float16* Uh  = (_Float16*)alloc((size_t)N * 64 * 2);
  _Float16* Vh  = (_Float16*)alloc((size_t)N * 64 * 2);
  _Float16* Yh  = (_Float16*)alloc((size_t)N * 64 * 2);
  _Float16* Bp1 = (_Float16*)alloc((size_t)128 * 192 * 2);
  _Float16* Bp2 = (_Float16*)alloc((size_t)64 * 192 * 2);
  _Float16* Bp3 = (_Float16*)alloc((size_t)64 * 48 * 2);

  // K1: histograms (+rank capture) + weight packs
  k1_hist_pack<<<551, 256, 0, stream>>>(ei, E, ES, part_src, part_dst, rank,
                                        W1, Wm, W2, Bp1, Bp2, Bp3, N);
  // K2: per-node reduce + per-slice prefix + block-local scan
  k2_reduce_scan<<<NB, 256, 0, stream>>>(part_src, part_dst, dis, cnt, exc, bsum, N);
  // K2b: scan block sums
  k2b_scan2<<<1, 256, 0, stream>>>(bsum, NB);
  // K3: LDS-free CSR fill + layer-1 GEMM
  k3_fill_gemm1<<<256 + 782, 256, 0, stream>>>(ei, E, ES, exc, bsum, part_dst, rank,
                                               (const unsigned short*)dis, ew,
                                               x, Bp1, b1, Ah, Uh, Vh, N);

  const int gmm  = (N + 63) / 64;           // 782
  const int g64c = (N * 8 + 255) / 256;     // 1563  (F=64, CH=8)
  const int g16c = (N * 4 + 255) / 256;     // 782   (F=16, CH=4)

  // Layer 1 laps (relu)
  lapA_kernel<64, 8><<<g64c, 256, 0, stream>>>(Vh, Uh, Yh, exc, cnt, bsum, ew, dis, N);
  lapB_kernel<64, 8, true, false><<<g64c, 256, 0, stream>>>(Yh, Ah, exc, cnt, bsum, ew, dis, Xh, N);

  // Layer 2: 64 -> 64, relu
  gemm_mfma_kernel<64, 64><<<gmm, 256, 0, stream>>>(Xh, Bp2, bm, Ah, Uh, Vh, N);
  lapA_kernel<64, 8><<<g64c, 256, 0, stream>>>(Vh, Uh, Yh, exc, cnt, bsum, ew, dis, N);
  lapB_kernel<64, 8, true, false><<<g64c, 256, 0, stream>>>(Yh, Ah, exc, cnt, bsum, ew, dis, Xh, N);

  // Layer 3: 64 -> 16, no relu, fp32 out
  gemm_mfma_kernel<64, 16><<<gmm, 256, 0, stream>>>(Xh, Bp3, b2, Ah, Uh, Vh, N);
  lapA_kernel<16, 4><<<g16c, 256, 0, stream>>>(Vh, Uh, Yh, exc, cnt, bsum, ew, dis, N);
  lapB_kernel<16, 4, false, true><<<g16c, 256, 0, stream>>>(Yh, Ah, exc, cnt, bsum, ew, dis, out, N);
}